// Round 9
// baseline (298.022 us; speedup 1.0000x reference)
//
#include <hip/hip_runtime.h>
#include <hip/hip_bf16.h>
#include <cstddef>

// Problem constants
constexpr int B = 2, L = 2048, D = 2048;
constexpr int H = 16, HKV = 4, HD = 128;
constexpr int GROUPS = H / HKV;          // 4
constexpr int KVD = 2 * HKV * HD;        // 1024
constexpr int M_ROWS = B * L;            // 4096
constexpr int QKVW = D + KVD;            // 3072 fused qkv width

typedef __attribute__((ext_vector_type(8))) short short8;   // 8 bf16 (4 VGPRs)
typedef __attribute__((ext_vector_type(4))) short s16x4;    // 4 bf16 (8B)
typedef __attribute__((ext_vector_type(4))) float f32x4;    // MFMA C/D

__device__ __forceinline__ short f2bf(float f) {
    union { float f; unsigned u; } v; v.f = f;
    unsigned r = v.u + 0x7FFFu + ((v.u >> 16) & 1u);   // RNE
    return (short)(r >> 16);
}

__device__ __forceinline__ float fast_exp2(float x) {
#if __has_builtin(__builtin_amdgcn_exp2f)
    return __builtin_amdgcn_exp2f(x);      // single v_exp_f32
#else
    return exp2f(x);
#endif
}

// RoPE-friendly in-head feature permutation:
// forward pi(d) = (d%16) + 32*(d/16)          (d < 64)
//              = (d%16) + 32*((d-64)/16) + 16 (d >= 64)
// => pair (i, i+64) sits at positions (p, p+16): same thread's col-slot pair.
// inverse (position pos -> original feature d):
__device__ __forceinline__ int invp(int pos) {
    const int b16 = pos >> 4, j = pos & 15;
    return ((b16 >> 1) << 4) + j + ((b16 & 1) << 6);
}

typedef __attribute__((address_space(1))) const void cg_void;
typedef __attribute__((address_space(3))) void lds_void;
__device__ __forceinline__ void gl_lds16(const void* g, void* l) {
    // async global->LDS: per-lane global gather, LDS dest = wave base + lane*16
    __builtin_amdgcn_global_load_lds((cg_void*)g, (lds_void*)l, 16, 0, 0);
}

// short waitcnt / barrier helpers
#define SBAR  __builtin_amdgcn_sched_barrier(0)
#define KBAR  __builtin_amdgcn_s_barrier()
#define LGKM(N) asm volatile("s_waitcnt lgkmcnt(" #N ")" ::: "memory")
#define VMC(N)  asm volatile("s_waitcnt vmcnt(" #N ")" ::: "memory")

// ---------------- fused fp32 -> bf16 casts + bias concat (one launch) ----------------
__global__ __launch_bounds__(256) void cast_all(
    const float* __restrict__ x, const float* __restrict__ Wq,
    const float* __restrict__ Wkv, const float* __restrict__ Wo,
    const float* __restrict__ bq, const float* __restrict__ bkv,
    short* __restrict__ xb, short* __restrict__ wqkvb, short* __restrict__ wob,
    float* __restrict__ bqkv)
{
    constexpr int n_x   = M_ROWS * D / 4;    // 2097152
    constexpr int n_wq  = D * D / 4;         // 1048576
    constexpr int n_wkv = KVD * D / 4;       // 524288
    constexpr int n_wo  = D * D / 4;         // 1048576
    constexpr int n_w   = n_x + n_wq + n_wkv + n_wo;   // 4718592
    constexpr int RPW   = D / 4;             // 512 float4 per weight row
    int i = blockIdx.x * 256 + threadIdx.x;
    if (i >= n_w) {
        const int j = i - n_w;               // [0, 768): bias float4
        float4 o;
#pragma unroll
        for (int e = 0; e < 4; ++e) {
            const int idx = j * 4 + e;
            float v;
            if (idx < D)                 v = bq[((idx >> 7) << 7) + invp(idx & 127)];
            else if (idx < D + HKV * HD) v = bkv[(((idx - D) >> 7) << 7) + invp((idx - D) & 127)];
            else                         v = bkv[idx - D];
            (&o.x)[e] = v;
        }
        ((float4*)bqkv)[j] = o;
        return;
    }
    const float* src; short* dst; int isrc;
    if (i < n_x) {
        src = x; dst = xb; isrc = i;
    } else if (i < n_x + n_wq) {
        i -= n_x; src = Wq; dst = wqkvb;
        const int fi = i / RPW, col = i % RPW;
        const int head = fi >> 7, pos = fi & 127;
        isrc = ((head << 7) + invp(pos)) * RPW + col;
    } else if (i < n_x + n_wq + n_wkv) {
        i -= n_x + n_wq; src = Wkv; dst = wqkvb + (size_t)D * D;
        const int fi = i / RPW, col = i % RPW;
        if (fi < HKV * HD) {      // k rows: permuted gather
            isrc = (((fi >> 7) << 7) + invp(fi & 127)) * RPW + col;
        } else {                  // v rows: identity
            isrc = i;
        }
    } else {
        i -= n_x + n_wq + n_wkv; src = Wo; dst = wob; isrc = i;
    }
    const float4 f = ((const float4*)src)[isrc];
    s16x4 s;
    s[0] = f2bf(f.x); s[1] = f2bf(f.y); s[2] = f2bf(f.z); s[3] = f2bf(f.w);
    ((s16x4*)dst)[i] = s;
}

// ---------------- 256x256 bf16 MFMA GEMM, counted-lgkm pipelined ----------------
// 512 threads = 8 waves (2M x 4N); wave tile 128x64; BK=64; LDS 128KB (2 dbuf).
// Per K-tile 2 phases (A-half each, 32 MFMA). Next phase's 8 A-frag ds_reads are
// issued BEFORE the current MFMA cluster; s_waitcnt lgkmcnt(8) drains only the
// current frags -> LDS pipe overlaps the matrix pipe. B single reg set (loaded
// once per K-tile, drained at P0's lgkm). 3 barriers / K-tile. vmcnt(4) counted
// (12 in flight steady-state). st_16x32 swizzle via pre-swizzled GLOBAL source.
// MODE 1: fused qkv epilogue (LDS-staged coalesced writeout).
template<int MODE>
__global__ __launch_bounds__(512, 2) void gemm256(
    const short* __restrict__ Ag, const short* __restrict__ Wg,
    const float* __restrict__ bias, float* __restrict__ C,
    const float* __restrict__ cosp, const float* __restrict__ sinp,
    short* __restrict__ qout, short* __restrict__ kout, short* __restrict__ vtout,
    int M, int N, int K)
{
    __shared__ __align__(1024) char smem[131072];

    const int tid = threadIdx.x;
    const int w = tid >> 6, lane = tid & 63;
    const int quad = lane >> 4, n16 = lane & 15;
    const int wr = w >> 2, wc = w & 3;

    // bijective XCD-aware swizzle (requires nwg % 8 == 0)
    const int nbx = gridDim.x;
    const int nwg = nbx * gridDim.y;
    int wg = blockIdx.y * nbx + blockIdx.x;
    wg = (wg & 7) * (nwg >> 3) + (wg >> 3);
    const int bm = (wg / nbx) << 8;
    const int bn = (wg % nbx) << 8;

    const int nkt = K >> 6;   // K-tiles of 64 (even, >=2)

    // swizzled within-subtile byte offset for frag ds_reads (st_16x32)
    const int sbo = n16 * 64 + ((quad * 16) ^ ((n16 & 8) << 2));

    // stage lane constants
    const int srow = lane >> 2;
    const int scol = ((lane & 3) * 8) ^ (((lane >> 5) & 1) << 4);

    f32x4 acc[8][4];
#pragma unroll
    for (int i = 0; i < 8; ++i)
#pragma unroll
        for (int j = 0; j < 4; ++j)
#pragma unroll
            for (int r = 0; r < 4; ++r) acc[i][j][r] = 0.f;

    short8 a0[4][2], a1[4][2], bfr[4][2];

#define STAGE_A(k0, cb, h)                                                     \
    { _Pragma("unroll") for (int j = 0; j < 2; ++j) {                          \
        const int s  = w + j * 8;                                              \
        const int u  = s >> 1;                                                 \
        const int rg = ((u >> 2) << 3) + ((h) << 2) + (u & 3);                 \
        const int gr = bm + (rg << 4) + srow;                                  \
        const int gc = (k0) + ((s & 1) << 5) + scol;                           \
        gl_lds16(Ag + (size_t)gr * K + gc,                                     \
                 smem + (cb) * 32768 + (h) * 16384 + (s << 10)); } }

#define STAGE_B(k0, cb, h)                                                     \
    { _Pragma("unroll") for (int j = 0; j < 2; ++j) {                          \
        const int s  = w + j * 8;                                              \
        const int u  = s >> 1;                                                 \
        const int rg = ((u >> 1) << 2) + ((h) << 1) + (u & 1);                 \
        const int gr = bn + (rg << 4) + srow;                                  \
        const int gc = (k0) + ((s & 1) << 5) + scol;                           \
        gl_lds16(Wg + (size_t)gr * K + gc,                                     \
                 smem + 65536 + (cb) * 32768 + (h) * 16384 + (s << 10)); } }

#define RD_B(CB)                                                               \
    { _Pragma("unroll") for (int nj = 0; nj < 4; ++nj)                         \
      _Pragma("unroll") for (int kk = 0; kk < 2; ++kk)                         \
        bfr[nj][kk] = *(const short8*)(smem + 65536 + (CB) * 32768 +           \
            (nj >> 1) * 16384 + ((((wc * 2 + (nj & 1)) * 2) + kk) << 10) + sbo); }

#define RD_A(DST, CB, MH)                                                      \
    { _Pragma("unroll") for (int mi = 0; mi < 4; ++mi)                         \
      _Pragma("unroll") for (int kk = 0; kk < 2; ++kk)                         \
        DST[mi][kk] = *(const short8*)(smem + (CB) * 32768 + (MH) * 16384 +    \
            ((((wr * 4 + mi) * 2) + kk) << 10) + sbo); }

#define MFMA32(MH, AR)                                                         \
    { __builtin_amdgcn_s_setprio(1);                                           \
      _Pragma("unroll") for (int mi = 0; mi < 4; ++mi)                         \
      _Pragma("unroll") for (int nj = 0; nj < 4; ++nj)                         \
      _Pragma("unroll") for (int kk = 0; kk < 2; ++kk)                         \
        acc[(MH) * 4 + mi][nj] = __builtin_amdgcn_mfma_f32_16x16x32_bf16(      \
            AR[mi][kk], bfr[nj][kk], acc[(MH) * 4 + mi][nj], 0, 0, 0);         \
      __builtin_amdgcn_s_setprio(0); }

    // ---- prologue: tile0 both halves (buf0) + tile1 h0 (buf1); preload a0(t0)
    STAGE_A(0, 0, 0); STAGE_B(0, 0, 0);
    STAGE_A(0, 0, 1); STAGE_B(0, 0, 1);
    if (nkt > 1) { STAGE_A(64, 1, 0); STAGE_B(64, 1, 0); VMC(4); }
    else         { VMC(0); }
    KBAR; SBAR;
    RD_A(a0, 0, 0);                       // 8 reads in flight

    for (int t = 0; t < nkt; t += 2) {
        const int k1 = (t + 1) << 6, k2 = (t + 2) << 6, k3 = (t + 3) << 6;
        const bool g2 = (t + 2) < nkt, g3 = (t + 3) < nkt;

        // ---- [t, P0] (buf0): MFMA h0; a1 reads overlap
        RD_B(0); SBAR;                    // +8 (must precede a1 for the count)
        RD_A(a1, 0, 1);                   // +8
        STAGE_A(k1, 1, 1); STAGE_B(k1, 1, 1);
        LGKM(8); SBAR;                    // a0+B done; a1 in flight
        MFMA32(0, a0);
        KBAR;
        // ---- [t, P1]: MFMA h1; a0(t+1) reads overlap
        if (g2) { STAGE_A(k2, 0, 0); STAGE_B(k2, 0, 0); VMC(4); }
        else    { VMC(0); }               // t+1 DMA drained
        KBAR; SBAR;
        RD_A(a0, 1, 0);                   // +8 (tile t+1, h0)
        LGKM(8); SBAR;                    // a1 done; a0' in flight
        MFMA32(1, a1);
        KBAR;
        // ---- [t+1, P0] (buf1)
        RD_B(1); SBAR;
        RD_A(a1, 1, 1);
        if (g2) { STAGE_A(k2, 0, 1); STAGE_B(k2, 0, 1); }
        LGKM(8); SBAR;
        MFMA32(0, a0);
        KBAR;
        // ---- [t+1, P1]
        if (g3) { STAGE_A(k3, 1, 0); STAGE_B(k3, 1, 0); VMC(4); }
        else    { VMC(0); }
        KBAR; SBAR;
        if (g2) { RD_A(a0, 0, 0); LGKM(8); } else { LGKM(0); }
        SBAR;
        MFMA32(1, a1);
        KBAR;
    }

#undef MFMA32
#undef RD_A
#undef RD_B
#undef STAGE_A
#undef STAGE_B

    if (MODE == 0) {
        // ---- plain epilogue: C = acc + bias (fp32)
#pragma unroll
        for (int mh = 0; mh < 2; ++mh)
#pragma unroll
            for (int mi2 = 0; mi2 < 4; ++mi2)
#pragma unroll
                for (int r = 0; r < 4; ++r) {
                    const int row = bm + wr * 128 + mh * 64 + mi2 * 16 + quad * 4 + r;
#pragma unroll
                    for (int nh = 0; nh < 2; ++nh)
#pragma unroll
                        for (int ni2 = 0; ni2 < 2; ++ni2) {
                            const int col = bn + wc * 64 + nh * 32 + ni2 * 16 + n16;
                            C[(size_t)row * N + col] =
                                acc[mh * 4 + mi2][nh * 2 + ni2][r] + bias[col];
                        }
                }
    } else {
        // ---- fused qkv epilogue, staged through the (now dead) 128KB smem as a
        // 256x256 bf16 tile T, then written out with coalesced short8 stores.
        short* const T = (short*)smem;
        __syncthreads();   // all waves past final K-loop barrier; LDS reusable
        if (bn < D + HKV * HD) {
            // -- q/k: bias + RoPE (pair in ni2=0/1 slots) -> T[row][col]
#pragma unroll
            for (int mh = 0; mh < 2; ++mh)
#pragma unroll
                for (int mi2 = 0; mi2 < 4; ++mi2)
#pragma unroll
                    for (int r = 0; r < 4; ++r) {
                        const int rl = wr * 128 + mh * 64 + mi2 * 16 + quad * 4 + r;
                        const int row = bm + rl;
                        const float* csrow = cosp + (size_t)row * HD;
                        const float* snrow = sinp + (size_t)row * HD;
                        const int sw = ((rl >> 2) & 7) << 4;   // byte-XOR bank swizzle
#pragma unroll
                        for (int nh = 0; nh < 2; ++nh) {
                            const int cl = wc * 64 + nh * 32 + n16;
                            const int iif = (wc & 1) * 32 + nh * 16 + n16;
                            const float a  = acc[mh * 4 + mi2][nh * 2 + 0][r] + bias[bn + cl];
                            const float bb = acc[mh * 4 + mi2][nh * 2 + 1][r] + bias[bn + cl + 16];
                            const float olo = a * csrow[iif]       - bb * snrow[iif];
                            const float ohi = bb * csrow[iif + 64] + a * snrow[iif + 64];
                            *(short*)((char*)T + ((rl * 512 + cl * 2) ^ sw))        = f2bf(olo);
                            *(short*)((char*)T + ((rl * 512 + (cl + 16) * 2) ^ sw)) = f2bf(ohi);
                        }
                    }
            __syncthreads();
            const bool isK = (bn >= D);
#pragma unroll
            for (int it = 0; it < 16; ++it) {
                const int idx = it * 512 + tid;
                const int rl = idx >> 5, c8 = idx & 31;
                const short8 v = *(const short8*)((char*)T +
                    ((rl * 512 + c8 * 16) ^ (((rl >> 2) & 7) << 4)));
                const int row = bm + rl;
                if (!isK) {
                    *(short8*)&qout[(size_t)row * D + bn + c8 * 8] = v;
                } else {
                    const int ck = bn - D + c8 * 8;
                    const int hk = ck >> 7, dk = ck & 127;
                    const int b_ = row >> 11, l_ = row & (L - 1);
                    *(short8*)&kout[((size_t)(b_ * HKV + hk) * L + l_) * HD + dk] = v;
                }
            }
        } else {
            // -- v: bias + cast -> T[cv][l] (transpose happens in LDS)
#pragma unroll
            for (int mh = 0; mh < 2; ++mh)
#pragma unroll
                for (int mi2 = 0; mi2 < 4; ++mi2) {
                    const int l0 = wr * 128 + mh * 64 + mi2 * 16 + quad * 4;
#pragma unroll
                    for (int nh = 0; nh < 2; ++nh)
#pragma unroll
                        for (int ni2 = 0; ni2 < 2; ++ni2) {
                            const int cl = wc * 64 + nh * 32 + ni2 * 16 + n16;
                            const float bs = bias[bn + cl];
                            s16x4 sv;
#pragma unroll
                            for (int r = 0; r < 4; ++r)
                                sv[r] = f2bf(acc[mh * 4 + mi2][nh * 2 + ni2][r] + bs);
                            *(s16x4*)((char*)T + ((cl * 512 + l0 * 2) ^ ((cl & 7) << 4))) = sv;
                        }
                }
            __syncthreads();
#pragma unroll
            for (int it = 0; it < 16; ++it) {
                const int idx = it * 512 + tid;
                const int cvr = idx >> 5, l8 = idx & 31;
                const short8 v = *(const short8*)((char*)T +
                    ((cvr * 512 + l8 * 16) ^ ((cvr & 7) << 4)));
                const int cv = bn - (D + HKV * HD) + cvr;
                const int hv = cv >> 7, dv = cv & 127;
                const int b_ = bm >> 11;
                const int lg = (bm & (L - 1)) + l8 * 8;
                *(short8*)&vtout[((size_t)(b_ * HKV + hv) * HD + dv) * L + lg] = v;
            }
        }
    }
}

// ---------------- 128x256 bf16 MFMA GEMM for the output projection ----------------
// Full-machine grid: (8, 32) = 256 blocks. 8 waves (2M x 4N), wave tile 64x64;
// BK=64; phases split by K-half. Counted-lgkm pipeline as in gemm256: next
// phase's 8 frag reads issued before current MFMA, lgkmcnt(8). LDS 96KB.
// Stage group = 3 loads; counted vmcnt(3).
__global__ __launch_bounds__(512, 2) void gemm_out(
    const short* __restrict__ Ag, const short* __restrict__ Wg,
    const float* __restrict__ bias, float* __restrict__ C,
    int M, int N, int K)
{
    __shared__ __align__(1024) char smem[98304];

    const int tid = threadIdx.x;
    const int w = tid >> 6, lane = tid & 63;
    const int quad = lane >> 4, n16 = lane & 15;
    const int wr = w >> 2, wc = w & 3;    // 2M x 4N

    const int nbx = gridDim.x;            // N/256
    const int nwg = nbx * gridDim.y;      // 256
    int wg = blockIdx.y * nbx + blockIdx.x;
    wg = (wg & 7) * (nwg >> 3) + (wg >> 3);
    const int bm = (wg / nbx) << 7;       // BM=128
    const int bn = (wg % nbx) << 8;       // BN=256

    const int nkt = K >> 6;

    const int sbo = n16 * 64 + ((quad * 16) ^ ((n16 & 8) << 2));
    const int srow = lane >> 2;
    const int scol = ((lane & 3) * 8) ^ (((lane >> 5) & 1) << 4);

    f32x4 acc[4][4];
#pragma unroll
    for (int i = 0; i < 4; ++i)
#pragma unroll
        for (int j = 0; j < 4; ++j)
#pragma unroll
            for (int r = 0; r < 4; ++r) acc[i][j][r] = 0.f;

    short8 oa0[4], ob0[4], oa1[4], ob1[4];

#define OSTAGE_A(k0, cb, kh)                                                   \
    { const int gr = bm + (w << 4) + srow;                                     \
      const int gc = (k0) + ((kh) << 5) + scol;                                \
      gl_lds16(Ag + (size_t)gr * K + gc,                                       \
               smem + (cb) * 16384 + (kh) * 8192 + (w << 10)); }

#define OSTAGE_B(k0, cb, kh)                                                   \
    { _Pragma("unroll") for (int j = 0; j < 2; ++j) {                          \
        const int s = w + j * 8;                                               \
        const int gr = bn + (s << 4) + srow;                                   \
        const int gc = (k0) + ((kh) << 5) + scol;                              \
        gl_lds16(Wg + (size_t)gr * K + gc,                                     \
                 smem + 32768 + (cb) * 32768 + (kh) * 16384 + (s << 10)); } }

#define ORD(AD, BD, CB, KH)                                                    \
    { _Pragma("unroll") for (int mi = 0; mi < 4; ++mi)                         \
        AD[mi] = *(const short8*)(smem + (CB) * 16384 + (KH) * 8192 +          \
            ((wr * 4 + mi) << 10) + sbo);                                      \
      _Pragma("unroll") for (int nj = 0; nj < 4; ++nj)                         \
        BD[nj] = *(const short8*)(smem + 32768 + (CB) * 32768 +                \
            (KH) * 16384 + ((wc * 4 + nj) << 10) + sbo); }

#define OMFMA(AD, BD)                                                          \
    { __builtin_amdgcn_s_setprio(1);                                           \
      _Pragma("unroll") for (int mi = 0; mi < 4; ++mi)                         \
      _Pragma("unroll") for (int nj = 0; nj < 4; ++nj)                         \
        acc[mi][nj] = __builtin_amdgcn_mfma_f32_16x16x32_bf16(                 \
            AD[mi], BD[nj], acc[mi][nj], 0, 0, 0);                             \
      __builtin_amdgcn_s_setprio(0); }

    // ---- prologue
    OSTAGE_A(0, 0, 0); OSTAGE_B(0, 0, 0);
    OSTAGE_A(0, 0, 1); OSTAGE_B(0, 0, 1);
    if (nkt > 1) { OSTAGE_A(64, 1, 0); OSTAGE_B(64, 1, 0); VMC(3); }
    else         { VMC(0); }
    KBAR; SBAR;
    ORD(oa0, ob0, 0, 0);                  // 8 reads in flight

    for (int t = 0; t < nkt; t += 2) {
        const int k1 = (t + 1) << 6, k2 = (t + 2) << 6, k3 = (t + 3) << 6;
        const bool g2 = (t + 2) < nkt, g3 = (t + 3) < nkt;

        // [t, P0] (buf0): MFMA kh0; kh1 reads overlap
        ORD(oa1, ob1, 0, 1);
        OSTAGE_A(k1, 1, 1); OSTAGE_B(k1, 1, 1);
        LGKM(8); SBAR;
        OMFMA(oa0, ob0);
        KBAR;
        // [t, P1]: MFMA kh1; (t+1,kh0) reads overlap
        if (g2) { OSTAGE_A(k2, 0, 0); OSTAGE_B(k2, 0, 0); VMC(3); }
        else    { VMC(0); }
        KBAR; SBAR;
        ORD(oa0, ob0, 1, 0);
        LGKM(8); SBAR;
        OMFMA(oa1, ob1);
        KBAR;
        // [t+1, P0] (buf1)
        ORD(oa1, ob1, 1, 1);
        if (g2) { OSTAGE_A(k2, 0, 1); OSTAGE_B(k2, 0, 1); }
        LGKM(8); SBAR;
        OMFMA(oa0, ob0);
        KBAR;
        // [t+1, P1]
        if (g3) { OSTAGE_A(k3, 1, 0); OSTAGE_B(k3, 1, 0); VMC(3); }
        else    { VMC(0); }
        KBAR; SBAR;
        if (g2) { ORD(oa0, ob0, 0, 0); LGKM(8); } else { LGKM(0); }
        SBAR;
        OMFMA(oa1, ob1);
        KBAR;
    }

#undef OMFMA
#undef ORD
#undef OSTAGE_A
#undef OSTAGE_B

    // ---- epilogue: C = acc + bias (fp32)
#pragma unroll
    for (int mi = 0; mi < 4; ++mi)
#pragma unroll
        for (int r = 0; r < 4; ++r) {
            const int row = bm + wr * 64 + mi * 16 + quad * 4 + r;
#pragma unroll
            for (int nj = 0; nj < 4; ++nj) {
                const int col = bn + wc * 64 + nj * 16 + n16;
                C[(size_t)row * N + col] = acc[mi][nj][r] + bias[col];
            }
        }
}

// ---------------- GQA MFMA flash attention, key-split 8-wave blocks ----------------
__global__ __launch_bounds__(512) void attn_mfma4(
    const short* __restrict__ qb_, const short* __restrict__ kb_,
    const short* __restrict__ vtb_, short* __restrict__ ob)
{
    // LDS layout: Ks[2][64*128] (32768B) | Vt[2][128*64] (32768B) | Pb[8][2][16][40] (20480B)
    // Rbuf overlay (front 4*64*76*4 = 77824B) used only after the post-loop barrier.
    __shared__ __align__(16) char smem[86016];
    short* const KsB  = (short*)smem;             // [2][8192]
    short* const VtB  = (short*)(smem + 32768);   // [2][8192]
    short* const PbB  = (short*)(smem + 65536);   // [8][2][16][40]
    float* const Rbuf = (float*)smem;             // overlay: [4][64][76]

    const int hkv = blockIdx.y, b = blockIdx.z;
    const int tid = threadIdx.x;
    const int w = tid >> 6, lane = tid & 63;
    const int quad = lane >> 4, n16 = lane & 15;
    const int h   = hkv * GROUPS + (w & 3);  // this wave's q-head
    const int kh  = (w >> 2) * 32;           // key-half offset within the 64-key tile
    const int khg = (w >> 2) * 4;            // granule offset for Vt slot selection

    const size_t kbase  = (size_t)(b * HKV + hkv) * L * HD;
    const size_t vtbase = (size_t)(b * HKV + hkv) * HD * L;
    const float c1 = 0.12751845f;    // (1/sqrt(128)) * log2(e)
    const float c0 = -28.853901f;    // -20 * log2(e)  (fixed-max offset)

    short8 ones;
#pragma unroll
    for (int i = 0; i < 8; ++i) ones[i] = (short)0x3F80;   // bf16 1.0

    // staging lane constants
    const int kr = lane >> 4;
    const int kg_sw = lane & 15;
    const int vr = lane >> 3;
    const int vg_sw = lane & 7;

    short* const myPb = PbB + w * (2 * 16 * 40);   // this wave's [2][16][40]

#pragma unroll 1
    for (int phase = 0; phase < 2; ++phase) {
        const int qidx = phase ? (63 - (int)blockIdx.x) : (int)blockIdx.x;
        const int qb0 = qidx * 32;
        const int ntiles = (qidx >> 1) + 1;

        // Q A-frags: 2 rowtiles x 4 ksteps
        short8 qf[2][4];
#pragma unroll
        for (int rt = 0; rt < 2; ++rt)
#pragma unroll
            for (int kk = 0; kk < 4; ++kk)
                qf[rt][kk] = *(const short8*)&qb_[
                    ((size_t)(b * L + qb0 + rt * 16 + n16)) * D + h * HD + kk * 32 + quad * 8];

        f32x4 oacc[2][8], lacc[2];
#pragma unroll
        for (int rt = 0; rt < 2; ++rt) {
#pragma unroll
            for (int r = 0; r < 4; ++r) lacc[rt][r] = 0.f;
#pragma unroll
            for (int nt = 0; nt < 8; ++nt)
#pragma unroll
                for (int r = 0; r < 4; ++r) oacc[rt][nt][r] = 0.f;
        }

        __syncthreads();   // prev phase fully done before staging overlays

        // stage tile 0 -> buf 0
        {
            const short* kg = kb_ + kbase;
            const short* vg = vtb_ + vtbase;
#pragma unroll
            for (int j = 0; j < 2; ++j) {
                const int chunk = w * 2 + j;
                const int r = chunk * 4 + kr;
                gl_lds16(kg + r * HD + (kg_sw ^ (r & 15)) * 8, KsB + chunk * 512);
            }
#pragma unroll
            for (int j = 0; j < 2; ++j) {
                const int chunk = w * 2 + j;
                const int d = chunk * 8 + vr;
                gl_lds16(vg + (size_t)d * L + (vg_sw ^ (d & 7)) * 8, VtB + chunk * 512);
            }
        }

        for (int kt = 0; kt < ntiles; ++kt) {
            const int buf = kt & 1;
            __syncthreads();   // drains DMA for tile kt; prev-buf readers done

            // prefetch tile kt+1 into the other buffer
            if (kt + 1 < ntiles) {
                const short* kg = kb_ + kbase + (size_t)((kt + 1) * 64) * HD;
                const short* vg = vtb_ + vtbase + (kt + 1) * 64;
#pragma unroll
                for (int j = 0; j < 2; ++j) {
                    const int chunk = w * 2 + j;
                    const int r = chunk * 4 + kr;
                    gl_lds16(kg + r * HD + (kg_sw ^ (r & 15)) * 8,
                             KsB + (buf ^ 1) * 8192 + chunk * 512);
                }
#pragma unroll
                for (int j = 0; j < 2; ++j) {
                    const int chunk = w * 2 + j;
                    const int d = chunk * 8 + vr;
                    gl_lds16(vg + (size_t)d * L + (vg_sw ^ (d & 7)) * 8,
                             VtB + (buf ^ 1) * 8192 + chunk * 512);
                }
            }

            const short* Ks = KsB + buf * 8192;
            const short* Vt = VtB + buf * 8192;

            // ---- S = Q K^T
            f32x4 s[2][2];
#pragma unroll
            for (int rt = 0; rt < 2; ++rt)
#pragma unroll
                for (int ktl = 0; ktl < 2; ++ktl)
#pragma unroll
                    for (int r = 0; r < 4; ++r) s[rt][ktl][r] = 0.f;
#pragma unroll
            for (int kk = 0; kk < 4; ++kk) {
                short8 kf[2];
#pragma unroll
                for (int ktl = 0; ktl < 2; ++ktl) {
                    const int row = kh + ktl * 16 + n16;
                    kf[ktl] = *(const short8*)&Ks[row * 128 + ((kk * 4 + quad) ^ n16) * 8];
                }
#pragma unroll
                for (int rt = 0; rt < 2; ++rt)
#pragma unroll
                    for (int ktl = 0; ktl < 2; ++ktl)
                        s[rt][ktl] = __builtin_amdgcn_mfma_f32_16x16x32_bf16(
                            qf[rt][kk], kf[ktl], s[rt][ktl], 0, 0, 0);
            }

            // ---- fixed-max softmax
            const bool lastt = (kt == ntiles - 1);
#pragma unroll
            for (int rt = 0; rt < 2; ++rt) {
#pragma unroll
                for (int ktl = 0; ktl < 2; ++ktl) {
                    const int key0 = kt * 64 + kh + ktl * 16 + n16;
#pragma unroll
                    for (int r = 0; r < 4; ++r) {
                        float sv = s[rt][ktl][r];
                        if (lastt) {
                            const int qi = qb0 + rt * 16 + quad * 4 + r;
                            sv = (key0 <= qi) ? sv : -1e30f;
                        }
                        const float e = fast_exp2(sv * c1 + c0);
                        myPb[(rt * 16 + quad * 4 + r) * 40 + ktl * 16 + n16] = f2bf(e);
                    }
                }
            }
            asm volatile("s_waitcnt lgkmcnt(0)" ::: "memory");   // Pb visible (same wave)

            // ---- P A-frags + l += P@ones + O += P V(half)
            short8 pf[2];
#pragma unroll
            for (int rt = 0; rt < 2; ++rt)
                pf[rt] = *(const short8*)&myPb[(rt * 16 + n16) * 40 + quad * 8];
#pragma unroll
            for (int rt = 0; rt < 2; ++rt)
                lacc[rt] = __builtin_amdgcn_mfma_f32_16x16x32_bf16(pf[rt], ones, lacc[rt], 0, 0, 0);
#pragma unroll
            for (int nt = 0; nt < 8; ++nt) {
                const short8 vf = *(const short8*)&Vt[
                    (nt * 16 + n16) * 64 + ((khg + quad) ^ (n16 & 7)) * 8];
#pragma unroll
                for (int rt = 0; rt < 2; ++rt)
                    oacc[rt][nt] = __builtin_amdgcn_mfma_f32_16x16x32_bf16(pf[rt], vf, oacc[rt][nt], 0, 0, 0);
            }
        }

        // ---- cross-half reduction
        __syncthreads();
        if (w >= 4) {
            float* rp = Rbuf + ((size_t)(w - 4) * 64 + lane) * 76;
#pragma unroll
            for (int rt = 0; rt < 2; ++rt)
#pragma unroll
                for (int nt = 0; nt < 8; ++nt)
                    *(f32x4*)&rp[(rt * 8 + nt) * 4] = oacc[rt][nt];
            *(f32x4*)&rp[64] = lacc[0];
            *(f32x4*)&rp[68] = lacc[1];
        }
        __syncthreads();
        if (w < 4) {
            const float* rp = Rbuf + ((size_t)w * 64 + lane) * 76;
#pragma unroll
            for (int rt = 0; rt < 2; ++rt) {
                const f32x4 lr = *(const f32x4*)&rp[64 + rt * 4];
#pragma unroll
                for (int r = 0; r < 4; ++r) lacc[rt][r] += lr[r];
#pragma unroll
                for (int nt = 0; nt < 8; ++nt) {
                    const f32x4 o2 = *(const f32x4*)&rp[(rt * 8 + nt) * 4];
#pragma unroll
                    for (int r = 0; r < 4; ++r) oacc[rt][nt][r] += o2[r];
                }
            }
            // ---- finalize: O/l, bf16 out
#pragma unroll
            for (int rt = 0; rt < 2; ++rt) {
#pragma unroll
                for (int r = 0; r < 4; ++r) {
                    const float inv = 1.0f / lacc[rt][r];
                    short* op = ob + ((size_t)(b * L + qb0 + rt * 16 + quad * 4 + r)) * D + h * HD + n16;
#pragma unroll
                    for (int nt = 0; nt < 8; ++nt) op[nt * 16] = f2bf(oacc[rt][nt][r] * inv);
                }
            }
        }
    }
}

// ---------------- launch ----------------
extern "C" void kernel_launch(void* const* d_in, const int* in_sizes, int n_in,
                              void* d_out, int out_size, void* d_ws, size_t ws_size,
                              hipStream_t stream)
{
    const float* x    = (const float*)d_in[0];
    const float* cosp = (const float*)d_in[1];
    const float* sinp = (const float*)d_in[2];
    const float* Wq   = (const float*)d_in[3];
    const float* bq   = (const float*)d_in[4];
    const float* Wkv  = (const float*)d_in[5];
    const float* bkv  = (const float*)d_in[6];
    const float* Wo   = (const float*)d_in[7];
    const float* bo   = (const float*)d_in[8];
    float* out = (float*)d_out;

    char* p = (char*)d_ws;
    short* x_bf    = (short*)p; p += (size_t)M_ROWS * D * 2;        // 16.8 MB (reused as attn out)
    short* wqkv_bf = (short*)p; p += (size_t)QKVW * D * 2;          // 12.6 MB
    short* wo_bf   = (short*)p; p += (size_t)D * D * 2;             //  8.4 MB
    float* b_qkv   = (float*)p; p += (size_t)QKVW * 4;              //  12 KB
    short* q_bf    = (short*)p; p += (size_t)M_ROWS * D * 2;        // 16.8 MB
    short* k_bf    = (short*)p; p += (size_t)M_ROWS * HKV * HD * 2; //  4.2 MB
    short* vt_bf   = (short*)p;                                     //  4.2 MB
    short* attn_bf = x_bf;   // x_bf dead after qkv GEMM

    dim3 blk(256);

    // fused cast + bias launch: x, Wq(perm), Wkv(k perm), Wo, b_qkv (18435 blocks)
    cast_all<<<dim3(18435), blk, 0, stream>>>(
        x, Wq, Wkv, Wo, bq, bkv, x_bf, wqkv_bf, wo_bf, b_qkv);

    // fused qkv GEMM + bias + RoPE + q/k/vt writes (12x16=192 blocks)
    gemm256<1><<<dim3(QKVW / 256, M_ROWS / 256), dim3(512), 0, stream>>>(
        x_bf, wqkv_bf, b_qkv, nullptr, cosp, sinp, q_bf, k_bf, vt_bf,
        M_ROWS, QKVW, D);

    attn_mfma4<<<dim3(32, HKV, B), dim3(512), 0, stream>>>(q_bf, k_bf, vt_bf, attn_bf);

    // out = attn @ Wo^T + bo   (8x32=256 blocks, full machine)
    gemm_out<<<dim3(D / 256, M_ROWS / 128), dim3(512), 0, stream>>>(
        attn_bf, wo_bf, bo, out, M_ROWS, D, D);
}

// Round 10
// 283.009 us; speedup vs baseline: 1.0530x; 1.0530x over previous
//
#include <hip/hip_runtime.h>
#include <hip/hip_bf16.h>
#include <cstddef>

// Problem constants
constexpr int B = 2, L = 2048, D = 2048;
constexpr int H = 16, HKV = 4, HD = 128;
constexpr int GROUPS = H / HKV;          // 4
constexpr int KVD = 2 * HKV * HD;        // 1024
constexpr int M_ROWS = B * L;            // 4096
constexpr int QKVW = D + KVD;            // 3072 fused qkv width

typedef __attribute__((ext_vector_type(8))) short short8;   // 8 bf16 (4 VGPRs)
typedef __attribute__((ext_vector_type(4))) short s16x4;    // 4 bf16 (8B)
typedef __attribute__((ext_vector_type(4))) float f32x4;    // MFMA C/D

__device__ __forceinline__ short f2bf(float f) {
    union { float f; unsigned u; } v; v.f = f;
    unsigned r = v.u + 0x7FFFu + ((v.u >> 16) & 1u);   // RNE
    return (short)(r >> 16);
}

__device__ __forceinline__ float fast_exp2(float x) {
#if __has_builtin(__builtin_amdgcn_exp2f)
    return __builtin_amdgcn_exp2f(x);      // single v_exp_f32
#else
    return exp2f(x);
#endif
}

// RoPE-friendly in-head feature permutation:
// forward pi(d) = (d%16) + 32*(d/16)          (d < 64)
//              = (d%16) + 32*((d-64)/16) + 16 (d >= 64)
// => pair (i, i+64) sits at positions (p, p+16): same thread's col-slot pair.
// inverse (position pos -> original feature d):
__device__ __forceinline__ int invp(int pos) {
    const int b16 = pos >> 4, j = pos & 15;
    return ((b16 >> 1) << 4) + j + ((b16 & 1) << 6);
}

typedef __attribute__((address_space(1))) const void cg_void;
typedef __attribute__((address_space(3))) void lds_void;
__device__ __forceinline__ void gl_lds16(const void* g, void* l) {
    // async global->LDS: per-lane global gather, LDS dest = wave base + lane*16
    __builtin_amdgcn_global_load_lds((cg_void*)g, (lds_void*)l, 16, 0, 0);
}

// ---------------- fused fp32 -> bf16 casts + bias concat (one launch) ----------------
__global__ __launch_bounds__(256) void cast_all(
    const float* __restrict__ x, const float* __restrict__ Wq,
    const float* __restrict__ Wkv, const float* __restrict__ Wo,
    const float* __restrict__ bq, const float* __restrict__ bkv,
    short* __restrict__ xb, short* __restrict__ wqkvb, short* __restrict__ wob,
    float* __restrict__ bqkv)
{
    constexpr int n_x   = M_ROWS * D / 4;    // 2097152
    constexpr int n_wq  = D * D / 4;         // 1048576
    constexpr int n_wkv = KVD * D / 4;       // 524288
    constexpr int n_wo  = D * D / 4;         // 1048576
    constexpr int n_w   = n_x + n_wq + n_wkv + n_wo;   // 4718592
    constexpr int RPW   = D / 4;             // 512 float4 per weight row
    int i = blockIdx.x * 256 + threadIdx.x;
    if (i >= n_w) {
        const int j = i - n_w;               // [0, 768): bias float4
        float4 o;
#pragma unroll
        for (int e = 0; e < 4; ++e) {
            const int idx = j * 4 + e;
            float v;
            if (idx < D)                 v = bq[((idx >> 7) << 7) + invp(idx & 127)];
            else if (idx < D + HKV * HD) v = bkv[(((idx - D) >> 7) << 7) + invp((idx - D) & 127)];
            else                         v = bkv[idx - D];
            (&o.x)[e] = v;
        }
        ((float4*)bqkv)[j] = o;
        return;
    }
    const float* src; short* dst; int isrc;
    if (i < n_x) {
        src = x; dst = xb; isrc = i;
    } else if (i < n_x + n_wq) {
        i -= n_x; src = Wq; dst = wqkvb;
        const int fi = i / RPW, col = i % RPW;
        const int head = fi >> 7, pos = fi & 127;
        isrc = ((head << 7) + invp(pos)) * RPW + col;
    } else if (i < n_x + n_wq + n_wkv) {
        i -= n_x + n_wq; src = Wkv; dst = wqkvb + (size_t)D * D;
        const int fi = i / RPW, col = i % RPW;
        if (fi < HKV * HD) {      // k rows: permuted gather
            isrc = (((fi >> 7) << 7) + invp(fi & 127)) * RPW + col;
        } else {                  // v rows: identity
            isrc = i;
        }
    } else {
        i -= n_x + n_wq + n_wkv; src = Wo; dst = wob; isrc = i;
    }
    const float4 f = ((const float4*)src)[isrc];
    s16x4 s;
    s[0] = f2bf(f.x); s[1] = f2bf(f.y); s[2] = f2bf(f.z); s[3] = f2bf(f.w);
    ((s16x4*)dst)[i] = s;
}

// ---------------- 256x256 bf16 MFMA GEMM, 2-phase-per-K-tile (T2+T4+T5) ----------------
// 512 threads = 8 waves (2M x 4N); wave tile 128x64; BK=64; LDS 128KB (2 dbuf).
// Per phase: ds_read A-half (8 b128) [+ all 8 B-frags on even phases] || issue
// 2 STAGE macros (4 gl_lds16) -> raw s_barrier -> lgkmcnt(0) -> setprio(1)
// 32 MFMA setprio(0) -> s_barrier. B-frags held in regs across the phase pair
// => LDS reads at the 24/thread/K-tile minimum; 4 barriers per K-tile.
// vmcnt(4) only at P1/P3 (12 in flight -> drains the tile about to be read).
// st_16x32 swizzle via pre-swizzled GLOBAL source (linear LDS dest).
// MODE 1: fused qkv epilogue (LDS-staged coalesced writeout).
// NOTE (r9 post-mortem): counted-lgkm deeper pipelining measured -15% here;
// this 2-phase schedule is the measured optimum for the 1-block/CU structure.
template<int MODE>
__global__ __launch_bounds__(512, 2) void gemm256(
    const short* __restrict__ Ag, const short* __restrict__ Wg,
    const float* __restrict__ bias, float* __restrict__ C,
    const float* __restrict__ cosp, const float* __restrict__ sinp,
    short* __restrict__ qout, short* __restrict__ kout, short* __restrict__ vtout,
    int M, int N, int K)
{
    __shared__ __align__(1024) char smem[131072];

    const int tid = threadIdx.x;
    const int w = tid >> 6, lane = tid & 63;
    const int quad = lane >> 4, n16 = lane & 15;
    const int wr = w >> 2, wc = w & 3;

    // bijective XCD-aware swizzle (requires nwg % 8 == 0)
    const int nbx = gridDim.x;
    const int nwg = nbx * gridDim.y;
    int wg = blockIdx.y * nbx + blockIdx.x;
    wg = (wg & 7) * (nwg >> 3) + (wg >> 3);
    const int bm = (wg / nbx) << 8;
    const int bn = (wg % nbx) << 8;

    const int nkt = K >> 6;   // K-tiles of 64 (must be even, >=2)

    // swizzled within-subtile byte offset for frag ds_reads (st_16x32)
    const int sbo = n16 * 64 + ((quad * 16) ^ ((n16 & 8) << 2));

    // stage lane constants: lane l fills subtile elems [l*8, l*8+8)
    const int srow = lane >> 2;                                  // row in 16-row group
    const int scol = ((lane & 3) * 8) ^ (((lane >> 5) & 1) << 4); // inverse-swizzled col

    f32x4 acc[8][4];
#pragma unroll
    for (int i = 0; i < 8; ++i)
#pragma unroll
        for (int j = 0; j < 4; ++j)
#pragma unroll
            for (int r = 0; r < 4; ++r) acc[i][j][r] = 0.f;

    short8 afr[4][2], bfr[4][2];

#define STAGE_A(k0, cb, h)                                                     \
    { _Pragma("unroll") for (int j = 0; j < 2; ++j) {                          \
        const int s  = w + j * 8;                                              \
        const int u  = s >> 1;                                                 \
        const int rg = ((u >> 2) << 3) + ((h) << 2) + (u & 3);                 \
        const int gr = bm + (rg << 4) + srow;                                  \
        const int gc = (k0) + ((s & 1) << 5) + scol;                           \
        gl_lds16(Ag + (size_t)gr * K + gc,                                     \
                 smem + (cb) * 32768 + (h) * 16384 + (s << 10)); } }

#define STAGE_B(k0, cb, h)                                                     \
    { _Pragma("unroll") for (int j = 0; j < 2; ++j) {                          \
        const int s  = w + j * 8;                                              \
        const int u  = s >> 1;                                                 \
        const int rg = ((u >> 1) << 2) + ((h) << 1) + (u & 1);                 \
        const int gr = bn + (rg << 4) + srow;                                  \
        const int gc = (k0) + ((s & 1) << 5) + scol;                           \
        gl_lds16(Wg + (size_t)gr * K + gc,                                     \
                 smem + 65536 + (cb) * 32768 + (h) * 16384 + (s << 10)); } }

// One phase: consume A-half MH of K-tile in buffer CB (32 MFMA). RDB=1 reloads
// all 8 B-frags (both halves); RDB=0 reuses the regs from the paired phase.
#define PHASE(CB, MH, RDB, STAGE_STMT, WAIT_STMT)                              \
    {                                                                          \
        if (RDB) {                                                             \
            _Pragma("unroll") for (int nj = 0; nj < 4; ++nj)                   \
            _Pragma("unroll") for (int kk = 0; kk < 2; ++kk)                   \
                bfr[nj][kk] = *(const short8*)(smem + 65536 + (CB) * 32768 +   \
                    (nj >> 1) * 16384 +                                        \
                    ((((wc * 2 + (nj & 1)) * 2) + kk) << 10) + sbo);           \
        }                                                                      \
        _Pragma("unroll") for (int mi2 = 0; mi2 < 4; ++mi2)                    \
        _Pragma("unroll") for (int kk = 0; kk < 2; ++kk)                       \
            afr[mi2][kk] = *(const short8*)(smem + (CB) * 32768 +              \
                (MH) * 16384 + ((((wr * 4 + mi2) * 2) + kk) << 10) + sbo);     \
        STAGE_STMT;                                                            \
        WAIT_STMT;                                                             \
        __builtin_amdgcn_s_barrier();                                          \
        asm volatile("s_waitcnt lgkmcnt(0)" ::: "memory");                     \
        __builtin_amdgcn_sched_barrier(0);                                     \
        __builtin_amdgcn_s_setprio(1);                                         \
        _Pragma("unroll") for (int mi2 = 0; mi2 < 4; ++mi2)                    \
        _Pragma("unroll") for (int nj = 0; nj < 4; ++nj)                       \
        _Pragma("unroll") for (int kk = 0; kk < 2; ++kk)                       \
            acc[(MH) * 4 + mi2][nj] =                                          \
                __builtin_amdgcn_mfma_f32_16x16x32_bf16(                       \
                    afr[mi2][kk], bfr[nj][kk], acc[(MH) * 4 + mi2][nj],        \
                    0, 0, 0);                                                  \
        __builtin_amdgcn_s_setprio(0);                                         \
        asm volatile("" ::: "memory");                                         \
        __builtin_amdgcn_s_barrier();                                          \
    }

#define NOP_WAIT asm volatile("" ::: "memory")

    // ---- prologue: tile0 all 4 halves (buf0) + tile1 A.h0/B.h0 (buf1)
    STAGE_A(0, 0, 0);
    STAGE_B(0, 0, 0);
    STAGE_A(0, 0, 1);
    STAGE_B(0, 0, 1);
    if (nkt > 1) {
        STAGE_A(64, 1, 0);
        STAGE_B(64, 1, 0);
        asm volatile("s_waitcnt vmcnt(4)" ::: "memory");   // tile0's 8 loads landed
    } else {
        asm volatile("s_waitcnt vmcnt(0)" ::: "memory");
    }
    __builtin_amdgcn_s_barrier();

    for (int t = 0; t < nkt; t += 2) {
        const int k1 = (t + 1) << 6, k2 = (t + 2) << 6, k3 = (t + 3) << 6;
        const bool g2 = (t + 2) < nkt, g3 = (t + 3) < nkt;

        // tile t (buf0): half0 then half1
        PHASE(0, 0, 1, { STAGE_A(k1, 1, 1); STAGE_B(k1, 1, 1); }, NOP_WAIT);
        PHASE(0, 1, 0, { if (g2) { STAGE_A(k2, 0, 0); STAGE_B(k2, 0, 0); } },
              { if (g2) asm volatile("s_waitcnt vmcnt(4)" ::: "memory");
                else    asm volatile("s_waitcnt vmcnt(0)" ::: "memory"); });   // t+1 ready

        // tile t+1 (buf1): half0 then half1
        PHASE(1, 0, 1, { if (g2) { STAGE_A(k2, 0, 1); STAGE_B(k2, 0, 1); } }, NOP_WAIT);
        PHASE(1, 1, 0, { if (g3) { STAGE_A(k3, 1, 0); STAGE_B(k3, 1, 0); } },
              { if (g3) asm volatile("s_waitcnt vmcnt(4)" ::: "memory");
                else    asm volatile("s_waitcnt vmcnt(0)" ::: "memory"); });   // t+2 ready
    }

#undef PHASE
#undef STAGE_A
#undef STAGE_B
#undef NOP_WAIT

    if (MODE == 0) {
        // ---- plain epilogue: C = acc + bias (fp32)
#pragma unroll
        for (int mh = 0; mh < 2; ++mh)
#pragma unroll
            for (int mi2 = 0; mi2 < 4; ++mi2)
#pragma unroll
                for (int r = 0; r < 4; ++r) {
                    const int row = bm + wr * 128 + mh * 64 + mi2 * 16 + quad * 4 + r;
#pragma unroll
                    for (int nh = 0; nh < 2; ++nh)
#pragma unroll
                        for (int ni2 = 0; ni2 < 2; ++ni2) {
                            const int col = bn + wc * 64 + nh * 32 + ni2 * 16 + n16;
                            C[(size_t)row * N + col] =
                                acc[mh * 4 + mi2][nh * 2 + ni2][r] + bias[col];
                        }
                }
    } else {
        // ---- fused qkv epilogue, staged through the (now dead) 128KB smem as a
        // 256x256 bf16 tile T, then written out with coalesced short8 stores.
        short* const T = (short*)smem;
        __syncthreads();   // all waves past final K-loop barrier; LDS reusable
        if (bn < D + HKV * HD) {
            // -- q/k: bias + RoPE (pair in ni2=0/1 slots) -> T[row][col]
#pragma unroll
            for (int mh = 0; mh < 2; ++mh)
#pragma unroll
                for (int mi2 = 0; mi2 < 4; ++mi2)
#pragma unroll
                    for (int r = 0; r < 4; ++r) {
                        const int rl = wr * 128 + mh * 64 + mi2 * 16 + quad * 4 + r;
                        const int row = bm + rl;
                        const float* csrow = cosp + (size_t)row * HD;
                        const float* snrow = sinp + (size_t)row * HD;
                        const int sw = ((rl >> 2) & 7) << 4;   // byte-XOR bank swizzle
#pragma unroll
                        for (int nh = 0; nh < 2; ++nh) {
                            const int cl = wc * 64 + nh * 32 + n16;
                            const int iif = (wc & 1) * 32 + nh * 16 + n16;
                            const float a  = acc[mh * 4 + mi2][nh * 2 + 0][r] + bias[bn + cl];
                            const float bb = acc[mh * 4 + mi2][nh * 2 + 1][r] + bias[bn + cl + 16];
                            const float olo = a * csrow[iif]       - bb * snrow[iif];
                            const float ohi = bb * csrow[iif + 64] + a * snrow[iif + 64];
                            *(short*)((char*)T + ((rl * 512 + cl * 2) ^ sw))        = f2bf(olo);
                            *(short*)((char*)T + ((rl * 512 + (cl + 16) * 2) ^ sw)) = f2bf(ohi);
                        }
                    }
            __syncthreads();
            const bool isK = (bn >= D);
#pragma unroll
            for (int it = 0; it < 16; ++it) {
                const int idx = it * 512 + tid;
                const int rl = idx >> 5, c8 = idx & 31;
                const short8 v = *(const short8*)((char*)T +
                    ((rl * 512 + c8 * 16) ^ (((rl >> 2) & 7) << 4)));
                const int row = bm + rl;
                if (!isK) {
                    *(short8*)&qout[(size_t)row * D + bn + c8 * 8] = v;
                } else {
                    const int ck = bn - D + c8 * 8;
                    const int hk = ck >> 7, dk = ck & 127;
                    const int b_ = row >> 11, l_ = row & (L - 1);
                    *(short8*)&kout[((size_t)(b_ * HKV + hk) * L + l_) * HD + dk] = v;
                }
            }
        } else {
            // -- v: bias + cast -> T[cv][l] (transpose happens in LDS)
#pragma unroll
            for (int mh = 0; mh < 2; ++mh)
#pragma unroll
                for (int mi2 = 0; mi2 < 4; ++mi2) {
                    const int l0 = wr * 128 + mh * 64 + mi2 * 16 + quad * 4;
#pragma unroll
                    for (int nh = 0; nh < 2; ++nh)
#pragma unroll
                        for (int ni2 = 0; ni2 < 2; ++ni2) {
                            const int cl = wc * 64 + nh * 32 + ni2 * 16 + n16;
                            const float bs = bias[bn + cl];
                            s16x4 sv;
#pragma unroll
                            for (int r = 0; r < 4; ++r)
                                sv[r] = f2bf(acc[mh * 4 + mi2][nh * 2 + ni2][r] + bs);
                            *(s16x4*)((char*)T + ((cl * 512 + l0 * 2) ^ ((cl & 7) << 4))) = sv;
                        }
                }
            __syncthreads();
#pragma unroll
            for (int it = 0; it < 16; ++it) {
                const int idx = it * 512 + tid;
                const int cvr = idx >> 5, l8 = idx & 31;
                const short8 v = *(const short8*)((char*)T +
                    ((cvr * 512 + l8 * 16) ^ ((cvr & 7) << 4)));
                const int cv = bn - (D + HKV * HD) + cvr;
                const int hv = cv >> 7, dv = cv & 127;
                const int b_ = bm >> 11;
                const int lg = (bm & (L - 1)) + l8 * 8;
                *(short8*)&vtout[((size_t)(b_ * HKV + hv) * HD + dv) * L + lg] = v;
            }
        }
    }
}

// ---------------- 128x256 bf16 MFMA GEMM for the output projection ----------------
// Full-machine grid: (N/256=8, M/128=32) = 256 blocks. 8 waves (2M x 4N), wave
// tile 64x64; BK=64; phases split by K-HALF (kh) so every wave is active each
// phase. LDS 96KB: A[2][2][8]x1KB (32KB) | B at +32768: [2][2][16]x1KB (64KB).
// Stage group = 3 loads (1 A + 2 B); counted vmcnt(3) at P1/P3 only.
// Same st_16x32 subtile swizzle as gemm256 (subtile-local, layout-independent).
__global__ __launch_bounds__(512, 2) void gemm_out(
    const short* __restrict__ Ag, const short* __restrict__ Wg,
    const float* __restrict__ bias, float* __restrict__ C,
    int M, int N, int K)
{
    __shared__ __align__(1024) char smem[98304];

    const int tid = threadIdx.x;
    const int w = tid >> 6, lane = tid & 63;
    const int quad = lane >> 4, n16 = lane & 15;
    const int wr = w >> 2, wc = w & 3;    // 2M x 4N

    const int nbx = gridDim.x;            // N/256
    const int nwg = nbx * gridDim.y;      // 256
    int wg = blockIdx.y * nbx + blockIdx.x;
    wg = (wg & 7) * (nwg >> 3) + (wg >> 3);
    const int bm = (wg / nbx) << 7;       // BM=128
    const int bn = (wg % nbx) << 8;       // BN=256

    const int nkt = K >> 6;

    const int sbo = n16 * 64 + ((quad * 16) ^ ((n16 & 8) << 2));
    const int srow = lane >> 2;
    const int scol = ((lane & 3) * 8) ^ (((lane >> 5) & 1) << 4);

    f32x4 acc[4][4];
#pragma unroll
    for (int i = 0; i < 4; ++i)
#pragma unroll
        for (int j = 0; j < 4; ++j)
#pragma unroll
            for (int r = 0; r < 4; ++r) acc[i][j][r] = 0.f;

    short8 afr[4], bfr[4];

#define OSTAGE_A(k0, cb, kh)                                                   \
    { const int gr = bm + (w << 4) + srow;                                     \
      const int gc = (k0) + ((kh) << 5) + scol;                                \
      gl_lds16(Ag + (size_t)gr * K + gc,                                       \
               smem + (cb) * 16384 + (kh) * 8192 + (w << 10)); }

#define OSTAGE_B(k0, cb, kh)                                                   \
    { _Pragma("unroll") for (int j = 0; j < 2; ++j) {                          \
        const int s = w + j * 8;                                               \
        const int gr = bn + (s << 4) + srow;                                   \
        const int gc = (k0) + ((kh) << 5) + scol;                              \
        gl_lds16(Wg + (size_t)gr * K + gc,                                     \
                 smem + 32768 + (cb) * 32768 + (kh) * 16384 + (s << 10)); } }

#define OPHASE(CB, KH, STAGE_STMT, WAIT_STMT)                                  \
    {                                                                          \
        _Pragma("unroll") for (int mi = 0; mi < 4; ++mi)                       \
            afr[mi] = *(const short8*)(smem + (CB) * 16384 + (KH) * 8192 +     \
                ((wr * 4 + mi) << 10) + sbo);                                  \
        _Pragma("unroll") for (int nj = 0; nj < 4; ++nj)                       \
            bfr[nj] = *(const short8*)(smem + 32768 + (CB) * 32768 +           \
                (KH) * 16384 + ((wc * 4 + nj) << 10) + sbo);                   \
        STAGE_STMT;                                                            \
        WAIT_STMT;                                                             \
        __builtin_amdgcn_s_barrier();                                          \
        asm volatile("s_waitcnt lgkmcnt(0)" ::: "memory");                     \
        __builtin_amdgcn_sched_barrier(0);                                     \
        __builtin_amdgcn_s_setprio(1);                                         \
        _Pragma("unroll") for (int mi = 0; mi < 4; ++mi)                       \
        _Pragma("unroll") for (int nj = 0; nj < 4; ++nj)                       \
            acc[mi][nj] = __builtin_amdgcn_mfma_f32_16x16x32_bf16(             \
                afr[mi], bfr[nj], acc[mi][nj], 0, 0, 0);                       \
        __builtin_amdgcn_s_setprio(0);                                         \
        asm volatile("" ::: "memory");                                         \
        __builtin_amdgcn_s_barrier();                                          \
    }

#define ONOP asm volatile("" ::: "memory")

    // ---- prologue: tile0 both K-halves (buf0, 6 loads) + tile1 kh0 (buf1, 3)
    OSTAGE_A(0, 0, 0);
    OSTAGE_B(0, 0, 0);
    OSTAGE_A(0, 0, 1);
    OSTAGE_B(0, 0, 1);
    if (nkt > 1) {
        OSTAGE_A(64, 1, 0);
        OSTAGE_B(64, 1, 0);
        asm volatile("s_waitcnt vmcnt(3)" ::: "memory");   // tile0's 6 loads landed
    } else {
        asm volatile("s_waitcnt vmcnt(0)" ::: "memory");
    }
    __builtin_amdgcn_s_barrier();

    for (int t = 0; t < nkt; t += 2) {
        const int k1 = (t + 1) << 6, k2 = (t + 2) << 6, k3 = (t + 3) << 6;
        const bool g2 = (t + 2) < nkt, g3 = (t + 3) < nkt;

        // tile t (buf0): kh0 then kh1
        OPHASE(0, 0, { OSTAGE_A(k1, 1, 1); OSTAGE_B(k1, 1, 1); }, ONOP);
        OPHASE(0, 1, { if (g2) { OSTAGE_A(k2, 0, 0); OSTAGE_B(k2, 0, 0); } },
               { if (g2) asm volatile("s_waitcnt vmcnt(3)" ::: "memory");
                 else    asm volatile("s_waitcnt vmcnt(0)" ::: "memory"); });  // t+1 ready

        // tile t+1 (buf1): kh0 then kh1
        OPHASE(1, 0, { if (g2) { OSTAGE_A(k2, 0, 1); OSTAGE_B(k2, 0, 1); } }, ONOP);
        OPHASE(1, 1, { if (g3) { OSTAGE_A(k3, 1, 0); OSTAGE_B(k3, 1, 0); } },
               { if (g3) asm volatile("s_waitcnt vmcnt(3)" ::: "memory");
                 else    asm volatile("s_waitcnt vmcnt(0)" ::: "memory"); });  // t+2 ready
    }

#undef OPHASE
#undef OSTAGE_A
#undef OSTAGE_B
#undef ONOP

    // ---- epilogue: C = acc + bias (fp32)
#pragma unroll
    for (int mi = 0; mi < 4; ++mi)
#pragma unroll
        for (int r = 0; r < 4; ++r) {
            const int row = bm + wr * 64 + mi * 16 + quad * 4 + r;
#pragma unroll
            for (int nj = 0; nj < 4; ++nj) {
                const int col = bn + wc * 64 + nj * 16 + n16;
                C[(size_t)row * N + col] = acc[mi][nj][r] + bias[col];
            }
        }
}

// ---------------- GQA MFMA flash attention, key-split 8-wave blocks ----------------
// Grid = (32, HKV, B) = 256 blocks; block = 8 waves (512 thr) -> 2 waves/SIMD.
// Waves 0-3 = 4 q-heads x keys [0,32) of each 64-key tile; waves 4-7 = same
// heads x keys [32,64). Fixed-max softmax => O/l partials add; one LDS
// reduction per phase (Rbuf overlays the dead Ks/Vt/Pb region).
// Balanced pairs {bx, 63-bx} (33 steps/block) + K/V double-buffer kept.
// T5: setprio(1) around the S / l / PV MFMA clusters — waves drift within a
// step (no intra-step barrier), so MFMA-vs-VALU arbitration has room (m191).
__global__ __launch_bounds__(512) void attn_mfma4(
    const short* __restrict__ qb_, const short* __restrict__ kb_,
    const short* __restrict__ vtb_, short* __restrict__ ob)
{
    // LDS layout: Ks[2][64*128] (32768B) | Vt[2][128*64] (32768B) | Pb[8][2][16][40] (20480B)
    // Rbuf overlay (front 4*64*76*4 = 77824B) used only after the post-loop barrier.
    __shared__ __align__(16) char smem[86016];
    short* const KsB  = (short*)smem;             // [2][8192]
    short* const VtB  = (short*)(smem + 32768);   // [2][8192]
    short* const PbB  = (short*)(smem + 65536);   // [8][2][16][40]
    float* const Rbuf = (float*)smem;             // overlay: [4][64][76]

    const int hkv = blockIdx.y, b = blockIdx.z;
    const int tid = threadIdx.x;
    const int w = tid >> 6, lane = tid & 63;
    const int quad = lane >> 4, n16 = lane & 15;
    const int h   = hkv * GROUPS + (w & 3);  // this wave's q-head
    const int kh  = (w >> 2) * 32;           // key-half offset within the 64-key tile
    const int khg = (w >> 2) * 4;            // granule offset for Vt slot selection

    const size_t kbase  = (size_t)(b * HKV + hkv) * L * HD;
    const size_t vtbase = (size_t)(b * HKV + hkv) * HD * L;
    const float c1 = 0.12751845f;    // (1/sqrt(128)) * log2(e)
    const float c0 = -28.853901f;    // -20 * log2(e)  (fixed-max offset)

    short8 ones;
#pragma unroll
    for (int i = 0; i < 8; ++i) ones[i] = (short)0x3F80;   // bf16 1.0

    // staging lane constants (granule swizzle; 2 K-chunks + 2 V-chunks per wave)
    const int kr = lane >> 4;                // K: row within 4-row chunk
    const int kg_sw = lane & 15;             // K: granule slot
    const int vr = lane >> 3;                // V: row within 8-row chunk
    const int vg_sw = lane & 7;

    short* const myPb = PbB + w * (2 * 16 * 40);   // this wave's [2][16][40]

#pragma unroll 1
    for (int phase = 0; phase < 2; ++phase) {
        const int qidx = phase ? (63 - (int)blockIdx.x) : (int)blockIdx.x;
        const int qb0 = qidx * 32;
        const int ntiles = (qidx >> 1) + 1;

        // Q A-frags: 2 rowtiles x 4 ksteps (both key-halves need all rows)
        short8 qf[2][4];
#pragma unroll
        for (int rt = 0; rt < 2; ++rt)
#pragma unroll
            for (int kk = 0; kk < 4; ++kk)
                qf[rt][kk] = *(const short8*)&qb_[
                    ((size_t)(b * L + qb0 + rt * 16 + n16)) * D + h * HD + kk * 32 + quad * 8];

        f32x4 oacc[2][8], lacc[2];
#pragma unroll
        for (int rt = 0; rt < 2; ++rt) {
#pragma unroll
            for (int r = 0; r < 4; ++r) lacc[rt][r] = 0.f;
#pragma unroll
            for (int nt = 0; nt < 8; ++nt)
#pragma unroll
                for (int r = 0; r < 4; ++r) oacc[rt][nt][r] = 0.f;
        }

        __syncthreads();   // prev phase fully done (incl. Rbuf reads) before staging overlays

        // stage tile 0 -> buf 0 (16 K-chunks + 16 V-chunks split over 8 waves)
        {
            const short* kg = kb_ + kbase;
            const short* vg = vtb_ + vtbase;
#pragma unroll
            for (int j = 0; j < 2; ++j) {
                const int chunk = w * 2 + j;
                const int r = chunk * 4 + kr;
                gl_lds16(kg + r * HD + (kg_sw ^ (r & 15)) * 8, KsB + chunk * 512);
            }
#pragma unroll
            for (int j = 0; j < 2; ++j) {
                const int chunk = w * 2 + j;
                const int d = chunk * 8 + vr;
                gl_lds16(vg + (size_t)d * L + (vg_sw ^ (d & 7)) * 8, VtB + chunk * 512);
            }
        }

        for (int kt = 0; kt < ntiles; ++kt) {
            const int buf = kt & 1;
            __syncthreads();   // drains DMA for tile kt; prev-buf readers done

            // prefetch tile kt+1 into the other buffer (hidden behind compute)
            if (kt + 1 < ntiles) {
                const short* kg = kb_ + kbase + (size_t)((kt + 1) * 64) * HD;
                const short* vg = vtb_ + vtbase + (kt + 1) * 64;
#pragma unroll
                for (int j = 0; j < 2; ++j) {
                    const int chunk = w * 2 + j;
                    const int r = chunk * 4 + kr;
                    gl_lds16(kg + r * HD + (kg_sw ^ (r & 15)) * 8,
                             KsB + (buf ^ 1) * 8192 + chunk * 512);
                }
#pragma unroll
                for (int j = 0; j < 2; ++j) {
                    const int chunk = w * 2 + j;
                    const int d = chunk * 8 + vr;
                    gl_lds16(vg + (size_t)d * L + (vg_sw ^ (d & 7)) * 8,
                             VtB + (buf ^ 1) * 8192 + chunk * 512);
                }
            }

            const short* Ks = KsB + buf * 8192;
            const short* Vt = VtB + buf * 8192;

            // ---- S = Q K^T : 2 rowtiles x 2 keytiles (this wave's key half) x 4 ksteps
            f32x4 s[2][2];
#pragma unroll
            for (int rt = 0; rt < 2; ++rt)
#pragma unroll
                for (int ktl = 0; ktl < 2; ++ktl)
#pragma unroll
                    for (int r = 0; r < 4; ++r) s[rt][ktl][r] = 0.f;
            __builtin_amdgcn_s_setprio(1);
#pragma unroll
            for (int kk = 0; kk < 4; ++kk) {
                short8 kf[2];
#pragma unroll
                for (int ktl = 0; ktl < 2; ++ktl) {
                    const int row = kh + ktl * 16 + n16;
                    kf[ktl] = *(const short8*)&Ks[row * 128 + ((kk * 4 + quad) ^ n16) * 8];
                }
#pragma unroll
                for (int rt = 0; rt < 2; ++rt)
#pragma unroll
                    for (int ktl = 0; ktl < 2; ++ktl)
                        s[rt][ktl] = __builtin_amdgcn_mfma_f32_16x16x32_bf16(
                            qf[rt][kk], kf[ktl], s[rt][ktl], 0, 0, 0);
            }
            __builtin_amdgcn_s_setprio(0);

            // ---- fixed-max softmax: e = exp2(s*c1 + c0); mask on last tile
            const bool lastt = (kt == ntiles - 1);
#pragma unroll
            for (int rt = 0; rt < 2; ++rt) {
#pragma unroll
                for (int ktl = 0; ktl < 2; ++ktl) {
                    const int key0 = kt * 64 + kh + ktl * 16 + n16;
#pragma unroll
                    for (int r = 0; r < 4; ++r) {
                        float sv = s[rt][ktl][r];
                        if (lastt) {
                            const int qi = qb0 + rt * 16 + quad * 4 + r;
                            sv = (key0 <= qi) ? sv : -1e30f;
                        }
                        const float e = fast_exp2(sv * c1 + c0);
                        myPb[(rt * 16 + quad * 4 + r) * 40 + ktl * 16 + n16] = f2bf(e);
                    }
                }
            }
            asm volatile("s_waitcnt lgkmcnt(0)" ::: "memory");   // Pb visible (same wave)

            // ---- P A-frags (16x32 each rowtile) + l += P@ones + O += P V(half)
            short8 pf[2];
#pragma unroll
            for (int rt = 0; rt < 2; ++rt)
                pf[rt] = *(const short8*)&myPb[(rt * 16 + n16) * 40 + quad * 8];
            __builtin_amdgcn_s_setprio(1);
#pragma unroll
            for (int rt = 0; rt < 2; ++rt)
                lacc[rt] = __builtin_amdgcn_mfma_f32_16x16x32_bf16(pf[rt], ones, lacc[rt], 0, 0, 0);
#pragma unroll
            for (int nt = 0; nt < 8; ++nt) {
                const short8 vf = *(const short8*)&Vt[
                    (nt * 16 + n16) * 64 + ((khg + quad) ^ (n16 & 7)) * 8];
#pragma unroll
                for (int rt = 0; rt < 2; ++rt)
                    oacc[rt][nt] = __builtin_amdgcn_mfma_f32_16x16x32_bf16(pf[rt], vf, oacc[rt][nt], 0, 0, 0);
            }
            __builtin_amdgcn_s_setprio(0);
        }

        // ---- cross-half reduction: upper key-half partials -> lower waves
        __syncthreads();                      // all waves done reading Ks/Vt/Pb (overlay safe)
        if (w >= 4) {
            float* rp = Rbuf + ((size_t)(w - 4) * 64 + lane) * 76;
#pragma unroll
            for (int rt = 0; rt < 2; ++rt)
#pragma unroll
                for (int nt = 0; nt < 8; ++nt)
                    *(f32x4*)&rp[(rt * 8 + nt) * 4] = oacc[rt][nt];
            *(f32x4*)&rp[64] = lacc[0];
            *(f32x4*)&rp[68] = lacc[1];
        }
        __syncthreads();
        if (w < 4) {
            const float* rp = Rbuf + ((size_t)w * 64 + lane) * 76;
#pragma unroll
            for (int rt = 0; rt < 2; ++rt) {
                const f32x4 lr = *(const f32x4*)&rp[64 + rt * 4];
#pragma unroll
                for (int r = 0; r < 4; ++r) lacc[rt][r] += lr[r];
#pragma unroll
                for (int nt = 0; nt < 8; ++nt) {
                    const f32x4 o2 = *(const f32x4*)&rp[(rt * 8 + nt) * 4];
#pragma unroll
                    for (int r = 0; r < 4; ++r) oacc[rt][nt][r] += o2[r];
                }
            }
            // ---- finalize: O/l, bf16 out
#pragma unroll
            for (int rt = 0; rt < 2; ++rt) {
#pragma unroll
                for (int r = 0; r < 4; ++r) {
                    const float inv = 1.0f / lacc[rt][r];
                    short* op = ob + ((size_t)(b * L + qb0 + rt * 16 + quad * 4 + r)) * D + h * HD + n16;
#pragma unroll
                    for (int nt = 0; nt < 8; ++nt) op[nt * 16] = f2bf(oacc[rt][nt][r] * inv);
                }
            }
        }
    }
}

// ---------------- launch ----------------
extern "C" void kernel_launch(void* const* d_in, const int* in_sizes, int n_in,
                              void* d_out, int out_size, void* d_ws, size_t ws_size,
                              hipStream_t stream)
{
    const float* x    = (const float*)d_in[0];
    const float* cosp = (const float*)d_in[1];
    const float* sinp = (const float*)d_in[2];
    const float* Wq   = (const float*)d_in[3];
    const float* bq   = (const float*)d_in[4];
    const float* Wkv  = (const float*)d_in[5];
    const float* bkv  = (const float*)d_in[6];
    const float* Wo   = (const float*)d_in[7];
    const float* bo   = (const float*)d_in[8];
    float* out = (float*)d_out;

    char* p = (char*)d_ws;
    short* x_bf    = (short*)p; p += (size_t)M_ROWS * D * 2;        // 16.8 MB (reused as attn out)
    short* wqkv_bf = (short*)p; p += (size_t)QKVW * D * 2;          // 12.6 MB
    short* wo_bf   = (short*)p; p += (size_t)D * D * 2;             //  8.4 MB
    float* b_qkv   = (float*)p; p += (size_t)QKVW * 4;              //  12 KB
    short* q_bf    = (short*)p; p += (size_t)M_ROWS * D * 2;        // 16.8 MB
    short* k_bf    = (short*)p; p += (size_t)M_ROWS * HKV * HD * 2; //  4.2 MB
    short* vt_bf   = (short*)p;                                     //  4.2 MB
    short* attn_bf = x_bf;   // x_bf dead after qkv GEMM

    dim3 blk(256);

    // fused cast + bias launch: x, Wq(perm), Wkv(k perm), Wo, b_qkv (18435 blocks)
    cast_all<<<dim3(18435), blk, 0, stream>>>(
        x, Wq, Wkv, Wo, bq, bkv, x_bf, wqkv_bf, wo_bf, b_qkv);

    // fused qkv GEMM + bias + RoPE + q/k/vt writes (12x16=192 blocks)
    gemm256<1><<<dim3(QKVW / 256, M_ROWS / 256), dim3(512), 0, stream>>>(
        x_bf, wqkv_bf, b_qkv, nullptr, cosp, sinp, q_bf, k_bf, vt_bf,
        M_ROWS, QKVW, D);

    attn_mfma4<<<dim3(32, HKV, B), dim3(512), 0, stream>>>(q_bf, k_bf, vt_bf, attn_bf);

    // out = attn @ Wo^T + bo   (8x32=256 blocks, full machine)
    gemm_out<<<dim3(D / 256, M_ROWS / 128), dim3(512), 0, stream>>>(
        attn_bf, wo_bf, bo, out, M_ROWS, D, D);
}

// Round 11
// 281.461 us; speedup vs baseline: 1.0588x; 1.0055x over previous
//
#include <hip/hip_runtime.h>
#include <hip/hip_bf16.h>
#include <cstddef>

// Problem constants
constexpr int B = 2, L = 2048, D = 2048;
constexpr int H = 16, HKV = 4, HD = 128;
constexpr int GROUPS = H / HKV;          // 4
constexpr int KVD = 2 * HKV * HD;        // 1024
constexpr int M_ROWS = B * L;            // 4096
constexpr int QKVW = D + KVD;            // 3072 fused qkv width

typedef __attribute__((ext_vector_type(8))) short short8;   // 8 bf16 (4 VGPRs)
typedef __attribute__((ext_vector_type(4))) short s16x4;    // 4 bf16 (8B)
typedef __attribute__((ext_vector_type(4))) float f32x4;    // MFMA C/D

__device__ __forceinline__ short f2bf(float f) {
    union { float f; unsigned u; } v; v.f = f;
    unsigned r = v.u + 0x7FFFu + ((v.u >> 16) & 1u);   // RNE
    return (short)(r >> 16);
}

__device__ __forceinline__ float fast_exp2(float x) {
#if __has_builtin(__builtin_amdgcn_exp2f)
    return __builtin_amdgcn_exp2f(x);      // single v_exp_f32
#else
    return exp2f(x);
#endif
}

// RoPE-friendly in-head feature permutation:
// forward pi(d) = (d%16) + 32*(d/16)          (d < 64)
//              = (d%16) + 32*((d-64)/16) + 16 (d >= 64)
// => pair (i, i+64) sits at positions (p, p+16): same thread's col-slot pair.
// inverse (position pos -> original feature d):
__device__ __forceinline__ int invp(int pos) {
    const int b16 = pos >> 4, j = pos & 15;
    return ((b16 >> 1) << 4) + j + ((b16 & 1) << 6);
}

typedef __attribute__((address_space(1))) const void cg_void;
typedef __attribute__((address_space(3))) void lds_void;
__device__ __forceinline__ void gl_lds16(const void* g, void* l) {
    // async global->LDS: per-lane global gather, LDS dest = wave base + lane*16
    __builtin_amdgcn_global_load_lds((cg_void*)g, (lds_void*)l, 16, 0, 0);
}

// ---------------- fused fp32 -> bf16 casts + bias concat (one launch) ----------------
__global__ __launch_bounds__(256) void cast_all(
    const float* __restrict__ x, const float* __restrict__ Wq,
    const float* __restrict__ Wkv, const float* __restrict__ Wo,
    const float* __restrict__ bq, const float* __restrict__ bkv,
    short* __restrict__ xb, short* __restrict__ wqkvb, short* __restrict__ wob,
    float* __restrict__ bqkv)
{
    constexpr int n_x   = M_ROWS * D / 4;    // 2097152
    constexpr int n_wq  = D * D / 4;         // 1048576
    constexpr int n_wkv = KVD * D / 4;       // 524288
    constexpr int n_wo  = D * D / 4;         // 1048576
    constexpr int n_w   = n_x + n_wq + n_wkv + n_wo;   // 4718592
    constexpr int RPW   = D / 4;             // 512 float4 per weight row
    int i = blockIdx.x * 256 + threadIdx.x;
    if (i >= n_w) {
        const int j = i - n_w;               // [0, 768): bias float4
        float4 o;
#pragma unroll
        for (int e = 0; e < 4; ++e) {
            const int idx = j * 4 + e;
            float v;
            if (idx < D)                 v = bq[((idx >> 7) << 7) + invp(idx & 127)];
            else if (idx < D + HKV * HD) v = bkv[(((idx - D) >> 7) << 7) + invp((idx - D) & 127)];
            else                         v = bkv[idx - D];
            (&o.x)[e] = v;
        }
        ((float4*)bqkv)[j] = o;
        return;
    }
    const float* src; short* dst; int isrc;
    if (i < n_x) {
        src = x; dst = xb; isrc = i;
    } else if (i < n_x + n_wq) {
        i -= n_x; src = Wq; dst = wqkvb;
        const int fi = i / RPW, col = i % RPW;
        const int head = fi >> 7, pos = fi & 127;
        isrc = ((head << 7) + invp(pos)) * RPW + col;
    } else if (i < n_x + n_wq + n_wkv) {
        i -= n_x + n_wq; src = Wkv; dst = wqkvb + (size_t)D * D;
        const int fi = i / RPW, col = i % RPW;
        if (fi < HKV * HD) {      // k rows: permuted gather
            isrc = (((fi >> 7) << 7) + invp(fi & 127)) * RPW + col;
        } else {                  // v rows: identity
            isrc = i;
        }
    } else {
        i -= n_x + n_wq + n_wkv; src = Wo; dst = wob; isrc = i;
    }
    const float4 f = ((const float4*)src)[isrc];
    s16x4 s;
    s[0] = f2bf(f.x); s[1] = f2bf(f.y); s[2] = f2bf(f.z); s[3] = f2bf(f.w);
    ((s16x4*)dst)[i] = s;
}

// ---------------- 256x256 bf16 MFMA GEMM, 2-phase-per-K-tile (T2+T4+T5) ----------------
// 512 threads = 8 waves (2M x 4N); wave tile 128x64; BK=64; LDS 128KB (2 dbuf).
// Per phase: ds_read A-half (8 b128) [+ all 8 B-frags on even phases] || issue
// 2 STAGE macros (4 gl_lds16) -> raw s_barrier -> lgkmcnt(0) -> setprio(1)
// 32 MFMA setprio(0) -> s_barrier. B-frags held in regs across the phase pair
// => LDS reads at the 24/thread/K-tile minimum; 4 barriers per K-tile.
// vmcnt(4) only at P1/P3 (12 in flight -> drains the tile about to be read).
// st_16x32 swizzle via pre-swizzled GLOBAL source (linear LDS dest).
// MODE 1: fused qkv epilogue (LDS-staged coalesced writeout).
// NOTE (r9 post-mortem): counted-lgkm deeper pipelining measured -15% here;
// this 2-phase schedule is the measured optimum for the 1-block/CU structure.
template<int MODE>
__global__ __launch_bounds__(512, 2) void gemm256(
    const short* __restrict__ Ag, const short* __restrict__ Wg,
    const float* __restrict__ bias, float* __restrict__ C,
    const float* __restrict__ cosp, const float* __restrict__ sinp,
    short* __restrict__ qout, short* __restrict__ kout, short* __restrict__ vtout,
    int M, int N, int K)
{
    __shared__ __align__(1024) char smem[131072];

    const int tid = threadIdx.x;
    const int w = tid >> 6, lane = tid & 63;
    const int quad = lane >> 4, n16 = lane & 15;
    const int wr = w >> 2, wc = w & 3;

    // bijective XCD-aware swizzle (requires nwg % 8 == 0)
    const int nbx = gridDim.x;
    const int nwg = nbx * gridDim.y;
    int wg = blockIdx.y * nbx + blockIdx.x;
    wg = (wg & 7) * (nwg >> 3) + (wg >> 3);
    const int bm = (wg / nbx) << 8;
    const int bn = (wg % nbx) << 8;

    const int nkt = K >> 6;   // K-tiles of 64 (must be even, >=2)

    // swizzled within-subtile byte offset for frag ds_reads (st_16x32)
    const int sbo = n16 * 64 + ((quad * 16) ^ ((n16 & 8) << 2));

    // stage lane constants: lane l fills subtile elems [l*8, l*8+8)
    const int srow = lane >> 2;                                  // row in 16-row group
    const int scol = ((lane & 3) * 8) ^ (((lane >> 5) & 1) << 4); // inverse-swizzled col

    f32x4 acc[8][4];
#pragma unroll
    for (int i = 0; i < 8; ++i)
#pragma unroll
        for (int j = 0; j < 4; ++j)
#pragma unroll
            for (int r = 0; r < 4; ++r) acc[i][j][r] = 0.f;

    short8 afr[4][2], bfr[4][2];

#define STAGE_A(k0, cb, h)                                                     \
    { _Pragma("unroll") for (int j = 0; j < 2; ++j) {                          \
        const int s  = w + j * 8;                                              \
        const int u  = s >> 1;                                                 \
        const int rg = ((u >> 2) << 3) + ((h) << 2) + (u & 3);                 \
        const int gr = bm + (rg << 4) + srow;                                  \
        const int gc = (k0) + ((s & 1) << 5) + scol;                           \
        gl_lds16(Ag + (size_t)gr * K + gc,                                     \
                 smem + (cb) * 32768 + (h) * 16384 + (s << 10)); } }

#define STAGE_B(k0, cb, h)                                                     \
    { _Pragma("unroll") for (int j = 0; j < 2; ++j) {                          \
        const int s  = w + j * 8;                                              \
        const int u  = s >> 1;                                                 \
        const int rg = ((u >> 1) << 2) + ((h) << 1) + (u & 1);                 \
        const int gr = bn + (rg << 4) + srow;                                  \
        const int gc = (k0) + ((s & 1) << 5) + scol;                           \
        gl_lds16(Wg + (size_t)gr * K + gc,                                     \
                 smem + 65536 + (cb) * 32768 + (h) * 16384 + (s << 10)); } }

// One phase: consume A-half MH of K-tile in buffer CB (32 MFMA). RDB=1 reloads
// all 8 B-frags (both halves); RDB=0 reuses the regs from the paired phase.
#define PHASE(CB, MH, RDB, STAGE_STMT, WAIT_STMT)                              \
    {                                                                          \
        if (RDB) {                                                             \
            _Pragma("unroll") for (int nj = 0; nj < 4; ++nj)                   \
            _Pragma("unroll") for (int kk = 0; kk < 2; ++kk)                   \
                bfr[nj][kk] = *(const short8*)(smem + 65536 + (CB) * 32768 +   \
                    (nj >> 1) * 16384 +                                        \
                    ((((wc * 2 + (nj & 1)) * 2) + kk) << 10) + sbo);           \
        }                                                                      \
        _Pragma("unroll") for (int mi2 = 0; mi2 < 4; ++mi2)                    \
        _Pragma("unroll") for (int kk = 0; kk < 2; ++kk)                       \
            afr[mi2][kk] = *(const short8*)(smem + (CB) * 32768 +              \
                (MH) * 16384 + ((((wr * 4 + mi2) * 2) + kk) << 10) + sbo);     \
        STAGE_STMT;                                                            \
        WAIT_STMT;                                                             \
        __builtin_amdgcn_s_barrier();                                          \
        asm volatile("s_waitcnt lgkmcnt(0)" ::: "memory");                     \
        __builtin_amdgcn_sched_barrier(0);                                     \
        __builtin_amdgcn_s_setprio(1);                                         \
        _Pragma("unroll") for (int mi2 = 0; mi2 < 4; ++mi2)                    \
        _Pragma("unroll") for (int nj = 0; nj < 4; ++nj)                       \
        _Pragma("unroll") for (int kk = 0; kk < 2; ++kk)                       \
            acc[(MH) * 4 + mi2][nj] =                                          \
                __builtin_amdgcn_mfma_f32_16x16x32_bf16(                       \
                    afr[mi2][kk], bfr[nj][kk], acc[(MH) * 4 + mi2][nj],        \
                    0, 0, 0);                                                  \
        __builtin_amdgcn_s_setprio(0);                                         \
        asm volatile("" ::: "memory");                                         \
        __builtin_amdgcn_s_barrier();                                          \
    }

#define NOP_WAIT asm volatile("" ::: "memory")

    // ---- prologue: tile0 all 4 halves (buf0) + tile1 A.h0/B.h0 (buf1)
    STAGE_A(0, 0, 0);
    STAGE_B(0, 0, 0);
    STAGE_A(0, 0, 1);
    STAGE_B(0, 0, 1);
    if (nkt > 1) {
        STAGE_A(64, 1, 0);
        STAGE_B(64, 1, 0);
        asm volatile("s_waitcnt vmcnt(4)" ::: "memory");   // tile0's 8 loads landed
    } else {
        asm volatile("s_waitcnt vmcnt(0)" ::: "memory");
    }
    __builtin_amdgcn_s_barrier();

    for (int t = 0; t < nkt; t += 2) {
        const int k1 = (t + 1) << 6, k2 = (t + 2) << 6, k3 = (t + 3) << 6;
        const bool g2 = (t + 2) < nkt, g3 = (t + 3) < nkt;

        // tile t (buf0): half0 then half1
        PHASE(0, 0, 1, { STAGE_A(k1, 1, 1); STAGE_B(k1, 1, 1); }, NOP_WAIT);
        PHASE(0, 1, 0, { if (g2) { STAGE_A(k2, 0, 0); STAGE_B(k2, 0, 0); } },
              { if (g2) asm volatile("s_waitcnt vmcnt(4)" ::: "memory");
                else    asm volatile("s_waitcnt vmcnt(0)" ::: "memory"); });   // t+1 ready

        // tile t+1 (buf1): half0 then half1
        PHASE(1, 0, 1, { if (g2) { STAGE_A(k2, 0, 1); STAGE_B(k2, 0, 1); } }, NOP_WAIT);
        PHASE(1, 1, 0, { if (g3) { STAGE_A(k3, 1, 0); STAGE_B(k3, 1, 0); } },
              { if (g3) asm volatile("s_waitcnt vmcnt(4)" ::: "memory");
                else    asm volatile("s_waitcnt vmcnt(0)" ::: "memory"); });   // t+2 ready
    }

#undef PHASE
#undef STAGE_A
#undef STAGE_B
#undef NOP_WAIT

    if (MODE == 0) {
        // ---- plain epilogue: C = acc + bias (fp32)
#pragma unroll
        for (int mh = 0; mh < 2; ++mh)
#pragma unroll
            for (int mi2 = 0; mi2 < 4; ++mi2)
#pragma unroll
                for (int r = 0; r < 4; ++r) {
                    const int row = bm + wr * 128 + mh * 64 + mi2 * 16 + quad * 4 + r;
#pragma unroll
                    for (int nh = 0; nh < 2; ++nh)
#pragma unroll
                        for (int ni2 = 0; ni2 < 2; ++ni2) {
                            const int col = bn + wc * 64 + nh * 32 + ni2 * 16 + n16;
                            C[(size_t)row * N + col] =
                                acc[mh * 4 + mi2][nh * 2 + ni2][r] + bias[col];
                        }
                }
    } else {
        // ---- fused qkv epilogue, staged through the (now dead) 128KB smem as a
        // 256x256 bf16 tile T, then written out with coalesced short8 stores.
        short* const T = (short*)smem;
        __syncthreads();   // all waves past final K-loop barrier; LDS reusable
        if (bn < D + HKV * HD) {
            // -- q/k: bias + RoPE (pair in ni2=0/1 slots) -> T[row][col]
#pragma unroll
            for (int mh = 0; mh < 2; ++mh)
#pragma unroll
                for (int mi2 = 0; mi2 < 4; ++mi2)
#pragma unroll
                    for (int r = 0; r < 4; ++r) {
                        const int rl = wr * 128 + mh * 64 + mi2 * 16 + quad * 4 + r;
                        const int row = bm + rl;
                        const float* csrow = cosp + (size_t)row * HD;
                        const float* snrow = sinp + (size_t)row * HD;
                        const int sw = ((rl >> 2) & 7) << 4;   // byte-XOR bank swizzle
#pragma unroll
                        for (int nh = 0; nh < 2; ++nh) {
                            const int cl = wc * 64 + nh * 32 + n16;
                            const int iif = (wc & 1) * 32 + nh * 16 + n16;
                            const float a  = acc[mh * 4 + mi2][nh * 2 + 0][r] + bias[bn + cl];
                            const float bb = acc[mh * 4 + mi2][nh * 2 + 1][r] + bias[bn + cl + 16];
                            const float olo = a * csrow[iif]       - bb * snrow[iif];
                            const float ohi = bb * csrow[iif + 64] + a * snrow[iif + 64];
                            *(short*)((char*)T + ((rl * 512 + cl * 2) ^ sw))        = f2bf(olo);
                            *(short*)((char*)T + ((rl * 512 + (cl + 16) * 2) ^ sw)) = f2bf(ohi);
                        }
                    }
            __syncthreads();
            const bool isK = (bn >= D);
#pragma unroll
            for (int it = 0; it < 16; ++it) {
                const int idx = it * 512 + tid;
                const int rl = idx >> 5, c8 = idx & 31;
                const short8 v = *(const short8*)((char*)T +
                    ((rl * 512 + c8 * 16) ^ (((rl >> 2) & 7) << 4)));
                const int row = bm + rl;
                if (!isK) {
                    *(short8*)&qout[(size_t)row * D + bn + c8 * 8] = v;
                } else {
                    const int ck = bn - D + c8 * 8;
                    const int hk = ck >> 7, dk = ck & 127;
                    const int b_ = row >> 11, l_ = row & (L - 1);
                    *(short8*)&kout[((size_t)(b_ * HKV + hk) * L + l_) * HD + dk] = v;
                }
            }
        } else {
            // -- v: bias + cast -> T[cv][l] (transpose happens in LDS)
#pragma unroll
            for (int mh = 0; mh < 2; ++mh)
#pragma unroll
                for (int mi2 = 0; mi2 < 4; ++mi2) {
                    const int l0 = wr * 128 + mh * 64 + mi2 * 16 + quad * 4;
#pragma unroll
                    for (int nh = 0; nh < 2; ++nh)
#pragma unroll
                        for (int ni2 = 0; ni2 < 2; ++ni2) {
                            const int cl = wc * 64 + nh * 32 + ni2 * 16 + n16;
                            const float bs = bias[bn + cl];
                            s16x4 sv;
#pragma unroll
                            for (int r = 0; r < 4; ++r)
                                sv[r] = f2bf(acc[mh * 4 + mi2][nh * 2 + ni2][r] + bs);
                            *(s16x4*)((char*)T + ((cl * 512 + l0 * 2) ^ ((cl & 7) << 4))) = sv;
                        }
                }
            __syncthreads();
#pragma unroll
            for (int it = 0; it < 16; ++it) {
                const int idx = it * 512 + tid;
                const int cvr = idx >> 5, l8 = idx & 31;
                const short8 v = *(const short8*)((char*)T +
                    ((cvr * 512 + l8 * 16) ^ ((cvr & 7) << 4)));
                const int cv = bn - (D + HKV * HD) + cvr;
                const int hv = cv >> 7, dv = cv & 127;
                const int b_ = bm >> 11;
                const int lg = (bm & (L - 1)) + l8 * 8;
                *(short8*)&vtout[((size_t)(b_ * HKV + hv) * HD + dv) * L + lg] = v;
            }
        }
    }
}

// ---------------- 128x256 bf16 MFMA GEMM for the output projection ----------------
// Full-machine grid: (N/256=8, M/128=32) = 256 blocks. 8 waves (2M x 4N), wave
// tile 64x64; BK=64; phases split by K-HALF (kh) so every wave is active each
// phase. LDS 96KB. Stage group = 3 loads; counted vmcnt(3) at P1/P3 only.
__global__ __launch_bounds__(512, 2) void gemm_out(
    const short* __restrict__ Ag, const short* __restrict__ Wg,
    const float* __restrict__ bias, float* __restrict__ C,
    int M, int N, int K)
{
    __shared__ __align__(1024) char smem[98304];

    const int tid = threadIdx.x;
    const int w = tid >> 6, lane = tid & 63;
    const int quad = lane >> 4, n16 = lane & 15;
    const int wr = w >> 2, wc = w & 3;    // 2M x 4N

    const int nbx = gridDim.x;            // N/256
    const int nwg = nbx * gridDim.y;      // 256
    int wg = blockIdx.y * nbx + blockIdx.x;
    wg = (wg & 7) * (nwg >> 3) + (wg >> 3);
    const int bm = (wg / nbx) << 7;       // BM=128
    const int bn = (wg % nbx) << 8;       // BN=256

    const int nkt = K >> 6;

    const int sbo = n16 * 64 + ((quad * 16) ^ ((n16 & 8) << 2));
    const int srow = lane >> 2;
    const int scol = ((lane & 3) * 8) ^ (((lane >> 5) & 1) << 4);

    f32x4 acc[4][4];
#pragma unroll
    for (int i = 0; i < 4; ++i)
#pragma unroll
        for (int j = 0; j < 4; ++j)
#pragma unroll
            for (int r = 0; r < 4; ++r) acc[i][j][r] = 0.f;

    short8 afr[4], bfr[4];

#define OSTAGE_A(k0, cb, kh)                                                   \
    { const int gr = bm + (w << 4) + srow;                                     \
      const int gc = (k0) + ((kh) << 5) + scol;                                \
      gl_lds16(Ag + (size_t)gr * K + gc,                                       \
               smem + (cb) * 16384 + (kh) * 8192 + (w << 10)); }

#define OSTAGE_B(k0, cb, kh)                                                   \
    { _Pragma("unroll") for (int j = 0; j < 2; ++j) {                          \
        const int s = w + j * 8;                                               \
        const int gr = bn + (s << 4) + srow;                                   \
        const int gc = (k0) + ((kh) << 5) + scol;                              \
        gl_lds16(Wg + (size_t)gr * K + gc,                                     \
                 smem + 32768 + (cb) * 32768 + (kh) * 16384 + (s << 10)); } }

#define OPHASE(CB, KH, STAGE_STMT, WAIT_STMT)                                  \
    {                                                                          \
        _Pragma("unroll") for (int mi = 0; mi < 4; ++mi)                       \
            afr[mi] = *(const short8*)(smem + (CB) * 16384 + (KH) * 8192 +     \
                ((wr * 4 + mi) << 10) + sbo);                                  \
        _Pragma("unroll") for (int nj = 0; nj < 4; ++nj)                       \
            bfr[nj] = *(const short8*)(smem + 32768 + (CB) * 32768 +           \
                (KH) * 16384 + ((wc * 4 + nj) << 10) + sbo);                   \
        STAGE_STMT;                                                            \
        WAIT_STMT;                                                             \
        __builtin_amdgcn_s_barrier();                                          \
        asm volatile("s_waitcnt lgkmcnt(0)" ::: "memory");                     \
        __builtin_amdgcn_sched_barrier(0);                                     \
        __builtin_amdgcn_s_setprio(1);                                         \
        _Pragma("unroll") for (int mi = 0; mi < 4; ++mi)                       \
        _Pragma("unroll") for (int nj = 0; nj < 4; ++nj)                       \
            acc[mi][nj] = __builtin_amdgcn_mfma_f32_16x16x32_bf16(             \
                afr[mi], bfr[nj], acc[mi][nj], 0, 0, 0);                       \
        __builtin_amdgcn_s_setprio(0);                                         \
        asm volatile("" ::: "memory");                                         \
        __builtin_amdgcn_s_barrier();                                          \
    }

#define ONOP asm volatile("" ::: "memory")

    // ---- prologue: tile0 both K-halves (buf0, 6 loads) + tile1 kh0 (buf1, 3)
    OSTAGE_A(0, 0, 0);
    OSTAGE_B(0, 0, 0);
    OSTAGE_A(0, 0, 1);
    OSTAGE_B(0, 0, 1);
    if (nkt > 1) {
        OSTAGE_A(64, 1, 0);
        OSTAGE_B(64, 1, 0);
        asm volatile("s_waitcnt vmcnt(3)" ::: "memory");   // tile0's 6 loads landed
    } else {
        asm volatile("s_waitcnt vmcnt(0)" ::: "memory");
    }
    __builtin_amdgcn_s_barrier();

    for (int t = 0; t < nkt; t += 2) {
        const int k1 = (t + 1) << 6, k2 = (t + 2) << 6, k3 = (t + 3) << 6;
        const bool g2 = (t + 2) < nkt, g3 = (t + 3) < nkt;

        // tile t (buf0): kh0 then kh1
        OPHASE(0, 0, { OSTAGE_A(k1, 1, 1); OSTAGE_B(k1, 1, 1); }, ONOP);
        OPHASE(0, 1, { if (g2) { OSTAGE_A(k2, 0, 0); OSTAGE_B(k2, 0, 0); } },
               { if (g2) asm volatile("s_waitcnt vmcnt(3)" ::: "memory");
                 else    asm volatile("s_waitcnt vmcnt(0)" ::: "memory"); });  // t+1 ready

        // tile t+1 (buf1): kh0 then kh1
        OPHASE(1, 0, { if (g2) { OSTAGE_A(k2, 0, 1); OSTAGE_B(k2, 0, 1); } }, ONOP);
        OPHASE(1, 1, { if (g3) { OSTAGE_A(k3, 1, 0); OSTAGE_B(k3, 1, 0); } },
               { if (g3) asm volatile("s_waitcnt vmcnt(3)" ::: "memory");
                 else    asm volatile("s_waitcnt vmcnt(0)" ::: "memory"); });  // t+2 ready
    }

#undef OPHASE
#undef OSTAGE_A
#undef OSTAGE_B
#undef ONOP

    // ---- epilogue: C = acc + bias (fp32)
#pragma unroll
    for (int mi = 0; mi < 4; ++mi)
#pragma unroll
        for (int r = 0; r < 4; ++r) {
            const int row = bm + wr * 64 + mi * 16 + quad * 4 + r;
#pragma unroll
            for (int nj = 0; nj < 4; ++nj) {
                const int col = bn + wc * 64 + nj * 16 + n16;
                C[(size_t)row * N + col] = acc[mi][nj][r] + bias[col];
            }
        }
}

// ---------------- GQA MFMA flash attention, QBLK=16 key-split, 2 blocks/CU ----------------
// Grid = (64, HKV, B) = 512 blocks; block = 8 waves (512 thr). Waves 0-3 =
// 4 q-heads x keys [0,32); waves 4-7 = same heads x keys [32,64). Each block
// does the balanced qidx pair {bx, 127-bx} (16 q-rows each): exactly 33-34
// k-tiles/block. LDS 75776B (<80KB) + __launch_bounds__(512,4) (VGPR<=128)
// => 2 co-resident blocks/CU = 4 waves/SIMD: one block's DMA drain overlaps
// the other's compute. Fixed-max softmax => O/l partials add across key
// halves; one LDS reduction per phase (Rbuf overlays dead Ks/Vt region).
__global__ __launch_bounds__(512, 4) void attn_mfma5(
    const short* __restrict__ qb_, const short* __restrict__ kb_,
    const short* __restrict__ vtb_, short* __restrict__ ob)
{
    // LDS: Ks[2][64*128] (32768B) | Vt[2][128*64] (32768B) | Pb[8][16][40] (10240B)
    // Rbuf overlay (front 4*64*40*4 = 40960B) used only after the post-loop barrier.
    __shared__ __align__(16) char smem[75776];
    short* const KsB  = (short*)smem;             // [2][8192]
    short* const VtB  = (short*)(smem + 32768);   // [2][8192]
    short* const PbB  = (short*)(smem + 65536);   // [8][16][40]
    float* const Rbuf = (float*)smem;             // overlay: [4][64][40]

    const int hkv = blockIdx.y, b = blockIdx.z;
    const int tid = threadIdx.x;
    const int w = tid >> 6, lane = tid & 63;
    const int quad = lane >> 4, n16 = lane & 15;
    const int h   = hkv * GROUPS + (w & 3);  // this wave's q-head
    const int kh  = (w >> 2) * 32;           // key-half offset within the 64-key tile
    const int khg = (w >> 2) * 4;            // granule offset for Vt slot selection

    const size_t kbase  = (size_t)(b * HKV + hkv) * L * HD;
    const size_t vtbase = (size_t)(b * HKV + hkv) * HD * L;
    const float c1 = 0.12751845f;    // (1/sqrt(128)) * log2(e)
    const float c0 = -28.853901f;    // -20 * log2(e)  (fixed-max offset)

    short8 ones;
#pragma unroll
    for (int i = 0; i < 8; ++i) ones[i] = (short)0x3F80;   // bf16 1.0

    // staging lane constants (granule swizzle; 2 K-chunks + 2 V-chunks per wave)
    const int kr = lane >> 4;                // K: row within 4-row chunk
    const int kg_sw = lane & 15;             // K: granule slot
    const int vr = lane >> 3;                // V: row within 8-row chunk
    const int vg_sw = lane & 7;

    short* const myPb = PbB + w * (16 * 40);   // this wave's [16][40]

#pragma unroll 1
    for (int phase = 0; phase < 2; ++phase) {
        const int qidx = phase ? (127 - (int)blockIdx.x) : (int)blockIdx.x;
        const int qb0 = qidx * 16;
        const int ntiles = (qidx >> 2) + 1;

        // Q A-frags: 1 rowtile x 4 ksteps
        short8 qf[4];
#pragma unroll
        for (int kk = 0; kk < 4; ++kk)
            qf[kk] = *(const short8*)&qb_[
                ((size_t)(b * L + qb0 + n16)) * D + h * HD + kk * 32 + quad * 8];

        f32x4 oacc[8], lacc;
#pragma unroll
        for (int r = 0; r < 4; ++r) lacc[r] = 0.f;
#pragma unroll
        for (int nt = 0; nt < 8; ++nt)
#pragma unroll
            for (int r = 0; r < 4; ++r) oacc[nt][r] = 0.f;

        __syncthreads();   // prev phase fully done (incl. Rbuf reads) before staging overlays

        // stage tile 0 -> buf 0 (16 K-chunks + 16 V-chunks split over 8 waves)
        {
            const short* kg = kb_ + kbase;
            const short* vg = vtb_ + vtbase;
#pragma unroll
            for (int j = 0; j < 2; ++j) {
                const int chunk = w * 2 + j;
                const int r = chunk * 4 + kr;
                gl_lds16(kg + r * HD + (kg_sw ^ (r & 15)) * 8, KsB + chunk * 512);
            }
#pragma unroll
            for (int j = 0; j < 2; ++j) {
                const int chunk = w * 2 + j;
                const int d = chunk * 8 + vr;
                gl_lds16(vg + (size_t)d * L + (vg_sw ^ (d & 7)) * 8, VtB + chunk * 512);
            }
        }

        for (int kt = 0; kt < ntiles; ++kt) {
            const int buf = kt & 1;
            __syncthreads();   // drains DMA for tile kt; prev-buf readers done

            // prefetch tile kt+1 into the other buffer (hidden behind compute)
            if (kt + 1 < ntiles) {
                const short* kg = kb_ + kbase + (size_t)((kt + 1) * 64) * HD;
                const short* vg = vtb_ + vtbase + (kt + 1) * 64;
#pragma unroll
                for (int j = 0; j < 2; ++j) {
                    const int chunk = w * 2 + j;
                    const int r = chunk * 4 + kr;
                    gl_lds16(kg + r * HD + (kg_sw ^ (r & 15)) * 8,
                             KsB + (buf ^ 1) * 8192 + chunk * 512);
                }
#pragma unroll
                for (int j = 0; j < 2; ++j) {
                    const int chunk = w * 2 + j;
                    const int d = chunk * 8 + vr;
                    gl_lds16(vg + (size_t)d * L + (vg_sw ^ (d & 7)) * 8,
                             VtB + (buf ^ 1) * 8192 + chunk * 512);
                }
            }

            const short* Ks = KsB + buf * 8192;
            const short* Vt = VtB + buf * 8192;

            // ---- S = Q K^T : 2 keytiles (this wave's key half) x 4 ksteps
            f32x4 s[2];
#pragma unroll
            for (int ktl = 0; ktl < 2; ++ktl)
#pragma unroll
                for (int r = 0; r < 4; ++r) s[ktl][r] = 0.f;
            __builtin_amdgcn_s_setprio(1);
#pragma unroll
            for (int kk = 0; kk < 4; ++kk) {
                short8 kf[2];
#pragma unroll
                for (int ktl = 0; ktl < 2; ++ktl) {
                    const int row = kh + ktl * 16 + n16;
                    kf[ktl] = *(const short8*)&Ks[row * 128 + ((kk * 4 + quad) ^ n16) * 8];
                }
#pragma unroll
                for (int ktl = 0; ktl < 2; ++ktl)
                    s[ktl] = __builtin_amdgcn_mfma_f32_16x16x32_bf16(
                        qf[kk], kf[ktl], s[ktl], 0, 0, 0);
            }
            __builtin_amdgcn_s_setprio(0);

            // ---- fixed-max softmax: e = exp2(s*c1 + c0); mask on last tile
            const bool lastt = (kt == ntiles - 1);
#pragma unroll
            for (int ktl = 0; ktl < 2; ++ktl) {
                const int key0 = kt * 64 + kh + ktl * 16 + n16;
#pragma unroll
                for (int r = 0; r < 4; ++r) {
                    float sv = s[ktl][r];
                    if (lastt) {
                        const int qi = qb0 + quad * 4 + r;
                        sv = (key0 <= qi) ? sv : -1e30f;
                    }
                    const float e = fast_exp2(sv * c1 + c0);
                    myPb[(quad * 4 + r) * 40 + ktl * 16 + n16] = f2bf(e);
                }
            }
            asm volatile("s_waitcnt lgkmcnt(0)" ::: "memory");   // Pb visible (same wave)

            // ---- P A-frag (16x32) + l += P@ones + O += P V(half)
            const short8 pf = *(const short8*)&myPb[n16 * 40 + quad * 8];
            __builtin_amdgcn_s_setprio(1);
            lacc = __builtin_amdgcn_mfma_f32_16x16x32_bf16(pf, ones, lacc, 0, 0, 0);
#pragma unroll
            for (int nt = 0; nt < 8; ++nt) {
                const short8 vf = *(const short8*)&Vt[
                    (nt * 16 + n16) * 64 + ((khg + quad) ^ (n16 & 7)) * 8];
                oacc[nt] = __builtin_amdgcn_mfma_f32_16x16x32_bf16(pf, vf, oacc[nt], 0, 0, 0);
            }
            __builtin_amdgcn_s_setprio(0);
        }

        // ---- cross-half reduction: upper key-half partials -> lower waves
        __syncthreads();                      // all waves done reading Ks/Vt/Pb (overlay safe)
        if (w >= 4) {
            float* rp = Rbuf + ((size_t)(w - 4) * 64 + lane) * 40;
#pragma unroll
            for (int nt = 0; nt < 8; ++nt)
                *(f32x4*)&rp[nt * 4] = oacc[nt];
            *(f32x4*)&rp[32] = lacc;
        }
        __syncthreads();
        if (w < 4) {
            const float* rp = Rbuf + ((size_t)w * 64 + lane) * 40;
            const f32x4 lr = *(const f32x4*)&rp[32];
#pragma unroll
            for (int r = 0; r < 4; ++r) lacc[r] += lr[r];
#pragma unroll
            for (int nt = 0; nt < 8; ++nt) {
                const f32x4 o2 = *(const f32x4*)&rp[nt * 4];
#pragma unroll
                for (int r = 0; r < 4; ++r) oacc[nt][r] += o2[r];
            }
            // ---- finalize: O/l, bf16 out
#pragma unroll
            for (int r = 0; r < 4; ++r) {
                const float inv = 1.0f / lacc[r];
                short* op = ob + ((size_t)(b * L + qb0 + quad * 4 + r)) * D + h * HD + n16;
#pragma unroll
                for (int nt = 0; nt < 8; ++nt) op[nt * 16] = f2bf(oacc[nt][r] * inv);
            }
        }
    }
}

// ---------------- launch ----------------
extern "C" void kernel_launch(void* const* d_in, const int* in_sizes, int n_in,
                              void* d_out, int out_size, void* d_ws, size_t ws_size,
                              hipStream_t stream)
{
    const float* x    = (const float*)d_in[0];
    const float* cosp = (const float*)d_in[1];
    const float* sinp = (const float*)d_in[2];
    const float* Wq   = (const float*)d_in[3];
    const float* bq   = (const float*)d_in[4];
    const float* Wkv  = (const float*)d_in[5];
    const float* bkv  = (const float*)d_in[6];
    const float* Wo   = (const float*)d_in[7];
    const float* bo   = (const float*)d_in[8];
    float* out = (float*)d_out;

    char* p = (char*)d_ws;
    short* x_bf    = (short*)p; p += (size_t)M_ROWS * D * 2;        // 16.8 MB (reused as attn out)
    short* wqkv_bf = (short*)p; p += (size_t)QKVW * D * 2;          // 12.6 MB
    short* wo_bf   = (short*)p; p += (size_t)D * D * 2;             //  8.4 MB
    float* b_qkv   = (float*)p; p += (size_t)QKVW * 4;              //  12 KB
    short* q_bf    = (short*)p; p += (size_t)M_ROWS * D * 2;        // 16.8 MB
    short* k_bf    = (short*)p; p += (size_t)M_ROWS * HKV * HD * 2; //  4.2 MB
    short* vt_bf   = (short*)p;                                     //  4.2 MB
    short* attn_bf = x_bf;   // x_bf dead after qkv GEMM

    dim3 blk(256);

    // fused cast + bias launch: x, Wq(perm), Wkv(k perm), Wo, b_qkv (18435 blocks)
    cast_all<<<dim3(18435), blk, 0, stream>>>(
        x, Wq, Wkv, Wo, bq, bkv, x_bf, wqkv_bf, wo_bf, b_qkv);

    // fused qkv GEMM + bias + RoPE + q/k/vt writes (12x16=192 blocks)
    gemm256<1><<<dim3(QKVW / 256, M_ROWS / 256), dim3(512), 0, stream>>>(
        x_bf, wqkv_bf, b_qkv, nullptr, cosp, sinp, q_bf, k_bf, vt_bf,
        M_ROWS, QKVW, D);

    // attention: QBLK=16 pairs, 512 blocks -> 2 co-resident blocks/CU
    attn_mfma5<<<dim3(64, HKV, B), dim3(512), 0, stream>>>(q_bf, k_bf, vt_bf, attn_bf);

    // out = attn @ Wo^T + bo   (8x32=256 blocks, full machine)
    gemm_out<<<dim3(D / 256, M_ROWS / 128), dim3(512), 0, stream>>>(
        attn_bf, wo_bf, bo, out, M_ROWS, D, D);
}